// Round 7
// baseline (3838.570 us; speedup 1.0000x reference)
//
#include <hip/hip_runtime.h>
#include <math.h>

// Problem constants (E,B,M,C) = (64, 512, 128, 128), sigma=0.5, eps=1e-6
#define MM   128
#define CC   128
#define EE   64
#define BB   512
#define LDT  132          // padded row stride for At in LDS (measured conflict-free: r4/r6 SQ_LDS_BANK_CONFLICT = 0)
#define SIG2 0.25f
#define EPSV 1e-6f

// LDS layout (floats): At[128][132] + 10 vectors of 128 + 24 scalars = 72,800 B
#define AT_OFF   0
#define VEC_BASE (128*LDT)
#define VEC(i)   (VEC_BASE + (i)*128)
// vec order: 0 vz, 1 vaz, 2 vw0(->w), 3 vt0, 4 vvv, 5 vu1(rr), 6 vt2(dl), 7 vuw, 8 vg1, 9 vg2
#define SC_OFF   (VEC_BASE + 10*128)
// scal: [0]=sig [1]=d2 [2]=s_uwg2 [3]=s_vg1 [4]=s_uwg1  [6..21]=epilogue wave sums [22]=GJ pivot
#define SMEM_FLOATS (SC_OFF + 24)
#define SMEM_BYTES  (SMEM_FLOATS * 4)

// ---------------------------------------------------------------------------
// 1024 threads = 16 waves: w = t>>6, l = t&63
//   r = 64*(w&1)+l (row owned), q = w>>1 (0..7), cb = 16*q (column chunk)
// REGISTERS: Areg[16], Ureg[16], Greg[16] = 48 state + ~50 temps ≈ 100 live.
// REGISTER CONTRACT (r1-r6 lesson): allocator lands at budget = 2x the
// waves_per_eu MIN (r6: (1,2)->128 worked). flat_work_group_size(1024,1024)
// additionally HARD-caps at 128 (16 waves must fit). waves_per_eu(2,4)
// -> 128 budget, ~100 live -> no spill. (r4 = same kernel shape with no
// attr -> heuristic chose 64 -> 5.8 GB scratch. This is the fix.)
// 16 waves -> 4 waves/SIMD: intra-phase latency hiding doubles vs r6.
// ---------------------------------------------------------------------------
#define KATTR __attribute__((amdgpu_flat_work_group_size(1024, 1024), amdgpu_waves_per_eu(2, 4)))

// In-place Gauss-Jordan inverse of (A A^T + SIG2*I), 1024 threads.
// A staged row-major in T=[128][LDT]; destroys T; leaves Ginv in T.
// Map: rg = t>>3, cq = t&7, ccb = 16*cq.   (verbatim from passing r4)
__device__ __forceinline__ void ginv_inplace(float* sm, const int t) {
    float* T   = sm + AT_OFF;
    float* piv = sm + SC_OFF + 22;
    const int rg = t >> 3, cq = t & 7, ccb = cq << 4;
    float Gacc[16];
    #pragma unroll
    for (int j = 0; j < 16; ++j) Gacc[j] = 0.f;
    #pragma unroll 1
    for (int cc = 0; cc < 32; ++cc) {
        const float4 ar = *(const float4*)&T[rg*LDT + 4*cc];
        #pragma unroll
        for (int j = 0; j < 16; ++j) {
            const float4 br = *(const float4*)&T[(ccb + j)*LDT + 4*cc];
            Gacc[j] += ar.x*br.x + ar.y*br.y + ar.z*br.z + ar.w*br.w;
        }
    }
    #pragma unroll
    for (int j = 0; j < 16; ++j)
        if (ccb + j == rg) Gacc[j] += SIG2;
    __syncthreads();
    #pragma unroll
    for (int j4 = 0; j4 < 4; ++j4) {
        float4 v; v.x = Gacc[4*j4]; v.y = Gacc[4*j4+1]; v.z = Gacc[4*j4+2]; v.w = Gacc[4*j4+3];
        *(float4*)&T[rg*LDT + ccb + 4*j4] = v;
    }
    #pragma unroll 1
    for (int k = 0; k < 128; ++k) {
        const int kq = k >> 4;
        __syncthreads();
        if (rg == k && cq == kq) piv[0] = 1.0f / T[k*LDT + k];
        __syncthreads();
        if (rg == k) {
            const float pinv = piv[0];
            #pragma unroll
            for (int j4 = 0; j4 < 4; ++j4) {
                float4 g = *(float4*)&T[k*LDT + ccb + 4*j4];
                g.x *= pinv; g.y *= pinv; g.z *= pinv; g.w *= pinv;
                *(float4*)&T[k*LDT + ccb + 4*j4] = g;
            }
            if (cq == kq) T[k*LDT + k] = pinv;   // identity-column trick
        }
        __syncthreads();
        const float f = (rg == k) ? 0.f : T[rg*LDT + k];
        __syncthreads();
        if (rg != k) {
            #pragma unroll
            for (int j4 = 0; j4 < 4; ++j4) {
                float4 own = *(float4*)&T[rg*LDT + ccb + 4*j4];
                const float4 pv = *(const float4*)&T[k*LDT + ccb + 4*j4];
                own.x -= f*pv.x; own.y -= f*pv.y; own.z -= f*pv.z; own.w -= f*pv.w;
                *(float4*)&T[rg*LDT + ccb + 4*j4] = own;
            }
            if (cq == kq) T[rg*LDT + k] -= f;    // blind gave f - f*pinv; want -f*pinv
        }
    }
    __syncthreads();
}

__global__ KATTR void gpm_setup(const float* __restrict__ mean0,
                                float* __restrict__ ginv0) {
    extern __shared__ float sm[];
    float* T = sm + AT_OFF;
    const int t = threadIdx.x;
    const int rg = t >> 3, cq = t & 7, ccb = cq << 4;
    const float* src = mean0 + rg*CC + ccb;
    #pragma unroll
    for (int j4 = 0; j4 < 4; ++j4)
        *(float4*)&T[rg*LDT + ccb + 4*j4] = *(const float4*)&src[4*j4];
    __syncthreads();
    ginv_inplace(sm, t);
    #pragma unroll
    for (int j4 = 0; j4 < 4; ++j4)
        *(float4*)&ginv0[rg*CC + ccb + 4*j4] = *(const float4*)&T[rg*LDT + ccb + 4*j4];
}

// 3-level shuffle (8-lane groups) then 1-in-8 lanes atomic into a scalar slot
#define SC_ADD(slot, val) { float v_ = (val);                                 \
    v_ += __shfl_xor(v_, 1, 64); v_ += __shfl_xor(v_, 2, 64);                 \
    v_ += __shfl_xor(v_, 4, 64);                                              \
    if ((l & 7) == 0) atomicAdd(&scal[slot], v_); }

__global__ KATTR void gpm_main(
        const float* __restrict__ zin, const float* __restrict__ mean0,
        const float* __restrict__ lvar, float* __restrict__ out,
        const float* __restrict__ ginv0, const int use_ws) {
    extern __shared__ float sm[];
    float* At  = sm + AT_OFF;
    float* vz  = sm + VEC(0);
    float* vaz = sm + VEC(1);
    float* vw0 = sm + VEC(2);   // becomes w after L5
    float* vt0 = sm + VEC(3);
    float* vvv = sm + VEC(4);
    float* vu1 = sm + VEC(5);   // pre-init az - SIG2*w0; becomes rr after L4
    float* vt2 = sm + VEC(6);   // pre-init z;            becomes dl after L6
    float* vuw = sm + VEC(7);
    float* vg1 = sm + VEC(8);
    float* vg2 = sm + VEC(9);
    float* scal = sm + SC_OFF;

    const int t = threadIdx.x, b = blockIdx.x;
    const int w = t >> 6, l = t & 63;
    const int r  = ((w & 1) << 6) | l;
    const int q  = w >> 1;
    const int cb = q << 4;

    // zero all vector slots (1280 floats) + scalar slots
    sm[VEC_BASE + t] = 0.f;
    if (t < 256) sm[VEC_BASE + 1024 + t] = 0.f;
    if (t < 24)  scal[t] = 0.f;

    const float pvar = expf(lvar[0]) + EPSV;

    float Areg[16], Ureg[16], Greg[16];
    {
        const float* src = mean0 + r*CC + cb;
        #pragma unroll
        for (int j4 = 0; j4 < 4; ++j4) {
            const float4 v = *(const float4*)&src[4*j4];
            Areg[4*j4] = v.x; Areg[4*j4+1] = v.y; Areg[4*j4+2] = v.z; Areg[4*j4+3] = v.w;
        }
    }
    #pragma unroll
    for (int j = 0; j < 16; ++j) Ureg[j] = (cb + j == r) ? pvar : 0.f;

    if (use_ws) {
        const float* src = ginv0 + r*CC + cb;
        #pragma unroll
        for (int j4 = 0; j4 < 4; ++j4) {
            const float4 v = *(const float4*)&src[4*j4];
            Greg[4*j4] = v.x; Greg[4*j4+1] = v.y; Greg[4*j4+2] = v.z; Greg[4*j4+3] = v.w;
        }
    } else {
        // fallback: stage A into At buffer, invert in place, read back
        #pragma unroll
        for (int j4 = 0; j4 < 4; ++j4) {
            float4 v; v.x = Areg[4*j4]; v.y = Areg[4*j4+1]; v.z = Areg[4*j4+2]; v.w = Areg[4*j4+3];
            *(float4*)&At[r*LDT + cb + 4*j4] = v;
        }
        __syncthreads();
        ginv_inplace(sm, t);
        #pragma unroll
        for (int j4 = 0; j4 < 4; ++j4) {
            const float4 v = *(const float4*)&At[r*LDT + cb + 4*j4];
            Greg[4*j4] = v.x; Greg[4*j4+1] = v.y; Greg[4*j4+2] = v.z; Greg[4*j4+3] = v.w;
        }
        __syncthreads();       // done reading Ginv before At is overwritten
    }
    // At = A^T (consecutive lanes -> consecutive addresses)
    #pragma unroll
    for (int j = 0; j < 16; ++j) At[(cb + j)*LDT + r] = Areg[j];
    if (t < 32)
        *(float4*)&vz[4*t] = *(const float4*)&zin[(size_t)b*CC + 4*t];
    __syncthreads();

    #pragma unroll 1
    for (int e = 0; e < EE; ++e) {
        // ---- L1: az = A z ; zero late accumulators (vuw,vg1,vg2) ; reset scalars ----
        {
            float s = 0.f;
            #pragma unroll
            for (int j4 = 0; j4 < 4; ++j4) {
                const float4 x = *(const float4*)&vz[cb + 4*j4];
                s += Areg[4*j4]*x.x + Areg[4*j4+1]*x.y + Areg[4*j4+2]*x.z + Areg[4*j4+3]*x.w;
            }
            atomicAdd(&vaz[r], s);
            if (t < 384) (sm + VEC(7))[t] = 0.f;       // vuw, vg1, vg2
            if (t == 512) { scal[0] = SIG2; scal[1] = 0.f; scal[2] = 0.f; scal[3] = 0.f; scal[4] = 0.f; }
        }
        __syncthreads();
        // ---- L2: w0 = Ginv az ----
        {
            float s = 0.f;
            #pragma unroll
            for (int j4 = 0; j4 < 4; ++j4) {
                const float4 x = *(const float4*)&vaz[cb + 4*j4];
                s += Greg[4*j4]*x.x + Greg[4*j4+1]*x.y + Greg[4*j4+2]*x.z + Greg[4*j4+3]*x.w;
            }
            atomicAdd(&vw0[r], s);
        }
        __syncthreads();
        // ---- L3: t0 = A^T w0 ; pre-init vu1 = az - SIG2*w0 ----
        {
            float s = 0.f;
            #pragma unroll
            for (int j4 = 0; j4 < 4; ++j4) {
                const float4 a = *(const float4*)&At[r*LDT + cb + 4*j4];
                const float4 x = *(const float4*)&vw0[cb + 4*j4];
                s += a.x*x.x + a.y*x.y + a.z*x.z + a.w*x.w;
            }
            atomicAdd(&vt0[r], s);
            if (t < 128) vu1[t] = vaz[t] - SIG2*vw0[t];
        }
        __syncthreads();
        // ---- L4: vu1 -= A t0   (after barrier: vu1 = rr = az - A A^T w0 - SIG2 w0) ----
        {
            float s = 0.f;
            #pragma unroll
            for (int j4 = 0; j4 < 4; ++j4) {
                const float4 x = *(const float4*)&vt0[cb + 4*j4];
                s += Areg[4*j4]*x.x + Areg[4*j4+1]*x.y + Areg[4*j4+2]*x.z + Areg[4*j4+3]*x.w;
            }
            atomicAdd(&vu1[r], -s);
        }
        __syncthreads();
        // ---- L5: vw0 += Ginv rr  (after barrier: vw0 = w) ; pre-init vt2 = z ----
        {
            float s = 0.f;
            #pragma unroll
            for (int j4 = 0; j4 < 4; ++j4) {
                const float4 x = *(const float4*)&vu1[cb + 4*j4];
                s += Greg[4*j4]*x.x + Greg[4*j4+1]*x.y + Greg[4*j4+2]*x.z + Greg[4*j4+3]*x.w;
            }
            atomicAdd(&vw0[r], s);
            if (t < 128) vt2[t] = vz[t];
        }
        __syncthreads();
        // ---- L6: vt2 -= A^T w (-> dl) ; uw = U w ; sig partial ----
        {
            float s1 = 0.f, s2 = 0.f;
            #pragma unroll
            for (int j4 = 0; j4 < 4; ++j4) {
                const float4 a = *(const float4*)&At[r*LDT + cb + 4*j4];
                const float4 x = *(const float4*)&vw0[cb + 4*j4];
                s1 += a.x*x.x + a.y*x.y + a.z*x.z + a.w*x.w;
                s2 += Ureg[4*j4]*x.x + Ureg[4*j4+1]*x.y + Ureg[4*j4+2]*x.z + Ureg[4*j4+3]*x.w;
            }
            atomicAdd(&vt2[r], -s1);
            atomicAdd(&vuw[r], s2);
            SC_ADD(0, s2 * vw0[r]);                    // sig partial
        }
        __syncthreads();
        // ---- L7: vv = A dl ; g2 = Ginv uw ; s_uwg2 ; d2 ----
        {
            float s1 = 0.f, s2 = 0.f;
            #pragma unroll
            for (int j4 = 0; j4 < 4; ++j4) {
                const float4 d4 = *(const float4*)&vt2[cb + 4*j4];
                const float4 u4 = *(const float4*)&vuw[cb + 4*j4];
                s1 += Areg[4*j4]*d4.x + Areg[4*j4+1]*d4.y + Areg[4*j4+2]*d4.z + Areg[4*j4+3]*d4.w;
                s2 += Greg[4*j4]*u4.x + Greg[4*j4+1]*u4.y + Greg[4*j4+2]*u4.z + Greg[4*j4+3]*u4.w;
            }
            atomicAdd(&vvv[r], s1);
            atomicAdd(&vg2[r], s2);
            SC_ADD(2, s2 * vuw[r]);                    // s_uwg2 partial
            if (t < 128) {
                float d_ = vt2[t]; d_ *= d_;
                d_ += __shfl_xor(d_, 1, 64); d_ += __shfl_xor(d_, 2, 64); d_ += __shfl_xor(d_, 4, 64);
                if ((l & 7) == 0) atomicAdd(&scal[1], d_);   // d2 partial
            }
        }
        __syncthreads();
        // ---- L8: g1 = Ginv vv ; s_vg1 ; s_uwg1 ----
        {
            float s = 0.f;
            #pragma unroll
            for (int j4 = 0; j4 < 4; ++j4) {
                const float4 x = *(const float4*)&vvv[cb + 4*j4];
                s += Greg[4*j4]*x.x + Greg[4*j4+1]*x.y + Greg[4*j4+2]*x.z + Greg[4*j4+3]*x.w;
            }
            atomicAdd(&vg1[r], s);
            SC_ADD(3, s * vvv[r]);                     // s_vg1 partial
            SC_ADD(4, s * vuw[r]);                     // s_uwg1 partial
        }
        __syncthreads();
        // ---- L9: rank updates of A (regs+At), U (regs), Ginv (regs) ----
        {
            const float sig = scal[0];
            const float inv_sig = 1.0f / sig;
            const float d2v = scal[1];
            const float s_uwg2 = scal[2], s_vg1 = scal[3], s_uwg1 = scal[4];
            // 2x2 Woodbury capacitance: G_new = G + v c^T + c v^T + d2 c c^T
            const float b11 = s_vg1 - d2v;
            const float b12 = 1.0f + s_uwg1*inv_sig;
            const float b22 = s_uwg2*inv_sig*inv_sig;
            const float idet = 1.0f / (b11*b22 - b12*b12);
            const float K11 = b22*idet, K12v = -b12*idet, K22 = b11*idet;
            const float k12s = K12v*inv_sig, k22s = K22*inv_sig*inv_sig;
            const float cr  = vuw[r]*inv_sig;
            const float g1r = vg1[r], g2r = vg2[r];
            const float ar_ = K11*g1r + k12s*g2r;
            const float br_ = k12s*g1r + k22s*g2r;
            #pragma unroll
            for (int j4 = 0; j4 < 4; ++j4) {
                const float4 dd = *(const float4*)&vt2[cb + 4*j4];
                Areg[4*j4]   += cr*dd.x; Areg[4*j4+1] += cr*dd.y;
                Areg[4*j4+2] += cr*dd.z; Areg[4*j4+3] += cr*dd.w;
                const float4 uu = *(const float4*)&vuw[cb + 4*j4];
                Ureg[4*j4]   -= cr*uu.x; Ureg[4*j4+1] -= cr*uu.y;
                Ureg[4*j4+2] -= cr*uu.z; Ureg[4*j4+3] -= cr*uu.w;
                const float4 q1 = *(const float4*)&vg1[cb + 4*j4];
                const float4 q2 = *(const float4*)&vg2[cb + 4*j4];
                Greg[4*j4]   -= ar_*q1.x + br_*q2.x;
                Greg[4*j4+1] -= ar_*q1.y + br_*q2.y;
                Greg[4*j4+2] -= ar_*q1.z + br_*q2.z;
                Greg[4*j4+3] -= ar_*q1.w + br_*q2.w;
            }
            // write-through A^T
            #pragma unroll
            for (int j = 0; j < 16; ++j) At[(cb + j)*LDT + r] = Areg[j];
            // zero next step's early accumulators: vaz,vw0,vt0,vvv (VEC(1)..VEC(4))
            if (t < 512) (sm + VEC(1))[t] = 0.f;
            if (t < 32 && e + 1 < EE)
                *(float4*)&vz[4*t] = *(const float4*)&zin[((size_t)(e+1)*BB + b)*CC + 4*t];
        }
        __syncthreads();
    }

    // epilogue: post_mean from Areg
    {
        float* dst = out + (size_t)b*(MM*CC) + r*CC + cb;
        #pragma unroll
        for (int j4 = 0; j4 < 4; ++j4) {
            float4 v; v.x = Areg[4*j4]; v.y = Areg[4*j4+1]; v.z = Areg[4*j4+2]; v.w = Areg[4*j4+3];
            *(float4*)&dst[4*j4] = v;
        }
    }
    // post_cov from Ureg + diag extraction (static indexing)
    float qd = 1.f;
    {
        float* dst = out + (size_t)BB*(MM*CC) + (size_t)b*(MM*MM) + r*MM + cb;
        #pragma unroll
        for (int j4 = 0; j4 < 4; ++j4) {
            float4 v; v.x = Ureg[4*j4]; v.y = Ureg[4*j4+1]; v.z = Ureg[4*j4+2]; v.w = Ureg[4*j4+3];
            *(float4*)&dst[4*j4] = v;
            if (cb + 4*j4     == r) qd = v.x;
            if (cb + 4*j4 + 1 == r) qd = v.y;
            if (cb + 4*j4 + 2 == r) qd = v.z;
            if (cb + 4*j4 + 3 == r) qd = v.w;
        }
    }
    // dkl = mean_b[ C*sum(q/p) + sum((A-A0)^2)/p - C*M + C*sum(log p - log q) ]
    {
        const float inv_p = 1.0f / pvar;
        float acc = 0.f;
        const float* src = mean0 + r*CC + cb;
        #pragma unroll
        for (int j4 = 0; j4 < 4; ++j4) {
            const float4 a0 = *(const float4*)&src[4*j4];
            const float dx = Areg[4*j4]   - a0.x, dy = Areg[4*j4+1] - a0.y;
            const float dz = Areg[4*j4+2] - a0.z, dw = Areg[4*j4+3] - a0.w;
            acc += dx*dx + dy*dy + dz*dz + dw*dw;
        }
        float local = acc * inv_p;
        if (q == (r >> 4))   // owner of diagonal element of row r
            local += (float)CC * (qd*inv_p + logf(pvar) - logf(qd));
        #pragma unroll
        for (int m2 = 1; m2 < 64; m2 <<= 1) local += __shfl_xor(local, m2, 64);
        if (l == 0) scal[6 + w] = local;
        __syncthreads();
        if (t == 0) {
            float tot = 0.f;
            #pragma unroll
            for (int i = 0; i < 16; ++i) tot += scal[6 + i];
            tot -= (float)(CC*MM);
            atomicAdd(out + (size_t)2*BB*MM*CC, tot * (1.0f/(float)BB));
        }
    }
}

extern "C" void kernel_launch(void* const* d_in, const int* in_sizes, int n_in,
                              void* d_out, int out_size, void* d_ws, size_t ws_size,
                              hipStream_t stream) {
    (void)in_sizes; (void)n_in; (void)out_size;
    const float* zin   = (const float*)d_in[0];
    const float* mean0 = (const float*)d_in[1];
    const float* lvar  = (const float*)d_in[2];
    float* out = (float*)d_out;
    float* dkl = out + (size_t)2*BB*MM*CC;
    const int use_ws = (d_ws != nullptr && ws_size >= (size_t)MM*MM*4) ? 1 : 0;
    float* ginv0 = (float*)d_ws;

    hipFuncSetAttribute((const void*)gpm_setup, hipFuncAttributeMaxDynamicSharedMemorySize, SMEM_BYTES);
    hipFuncSetAttribute((const void*)gpm_main,  hipFuncAttributeMaxDynamicSharedMemorySize, SMEM_BYTES);

    hipMemsetAsync(dkl, 0, sizeof(float), stream);
    if (use_ws)
        gpm_setup<<<1, 1024, SMEM_BYTES, stream>>>(mean0, ginv0);
    gpm_main<<<BB, 1024, SMEM_BYTES, stream>>>(zin, mean0, lvar, out, ginv0, use_ws);
}

// Round 8
// 2749.019 us; speedup vs baseline: 1.3963x; 1.3963x over previous
//
#include <hip/hip_runtime.h>
#include <math.h>

// Problem constants (E,B,M,C) = (64, 512, 128, 128), sigma=0.5, eps=1e-6
#define MM   128
#define CC   128
#define EE   64
#define BB   512
#define LDT  132          // padded row stride (measured conflict-free: r4/r6/r7 SQ_LDS_BANK_CONFLICT = 0)
#define SIG2 0.25f
#define EPSV 1e-6f

// LDS layout (floats): At[128][132] + U[128][132] + 10 vectors of 128 + 24 scalars
#define AT_OFF   0
#define U_OFF    (128*LDT)
#define VEC_BASE (2*128*LDT)
#define VEC(i)   (VEC_BASE + (i)*128)
// vec order: 0 vz, 1 vaz, 2 vw0(->w), 3 vt0, 4 vvv, 5 vu1(rr), 6 vt2(dl), 7 vuw, 8 vg1, 9 vg2
#define SC_OFF   (VEC_BASE + 10*128)
// scal: [0]=sig [1]=d2 [2]=s_uwg2 [3]=s_vg1 [4]=s_uwg1  [6..21]=epilogue wave sums [22]=GJ pivot
#define SMEM_FLOATS (SC_OFF + 24)
#define SMEM_BYTES  (SMEM_FLOATS * 4)    // 140,384 B -> 1 block/CU, 16 waves resident

// ---------------------------------------------------------------------------
// 1024 threads = 16 waves: w = t>>6, l = t&63
//   r = 64*(w&1)+l (row owned), q = w>>1 (0..7), cb = 16*q (column chunk)
// REGISTERS: Areg[16] + Greg[16] = 32 state.  U LIVES IN LDS (coldest state:
// 1 matvec + 1 rmw + epilogue).  Live set ~60 regs.
// ALLOCATOR LAW (r1-r7): 1024-thr blocks get a 64-VGPR budget no matter what
// attribute is used (r4, r7: spilled 48-state kernels). This kernel is
// DESIGNED to fit 64. 16 waves = 4/SIMD doubles r6's latency hiding.
// ---------------------------------------------------------------------------
#define KATTR __attribute__((amdgpu_flat_work_group_size(1024, 1024)))

// In-place Gauss-Jordan inverse of (A A^T + SIG2*I), 1024 threads.
// A staged row-major in T=[128][LDT]; destroys T; leaves Ginv in T.
// Map: rg = t>>3, cq = t&7, ccb = 16*cq.   (verbatim from passing r4/r7)
__device__ __forceinline__ void ginv_inplace(float* sm, const int t) {
    float* T   = sm + AT_OFF;
    float* piv = sm + SC_OFF + 22;
    const int rg = t >> 3, cq = t & 7, ccb = cq << 4;
    float Gacc[16];
    #pragma unroll
    for (int j = 0; j < 16; ++j) Gacc[j] = 0.f;
    #pragma unroll 1
    for (int cc = 0; cc < 32; ++cc) {
        const float4 ar = *(const float4*)&T[rg*LDT + 4*cc];
        #pragma unroll
        for (int j = 0; j < 16; ++j) {
            const float4 br = *(const float4*)&T[(ccb + j)*LDT + 4*cc];
            Gacc[j] += ar.x*br.x + ar.y*br.y + ar.z*br.z + ar.w*br.w;
        }
    }
    #pragma unroll
    for (int j = 0; j < 16; ++j)
        if (ccb + j == rg) Gacc[j] += SIG2;
    __syncthreads();
    #pragma unroll
    for (int j4 = 0; j4 < 4; ++j4) {
        float4 v; v.x = Gacc[4*j4]; v.y = Gacc[4*j4+1]; v.z = Gacc[4*j4+2]; v.w = Gacc[4*j4+3];
        *(float4*)&T[rg*LDT + ccb + 4*j4] = v;
    }
    #pragma unroll 1
    for (int k = 0; k < 128; ++k) {
        const int kq = k >> 4;
        __syncthreads();
        if (rg == k && cq == kq) piv[0] = 1.0f / T[k*LDT + k];
        __syncthreads();
        if (rg == k) {
            const float pinv = piv[0];
            #pragma unroll
            for (int j4 = 0; j4 < 4; ++j4) {
                float4 g = *(float4*)&T[k*LDT + ccb + 4*j4];
                g.x *= pinv; g.y *= pinv; g.z *= pinv; g.w *= pinv;
                *(float4*)&T[k*LDT + ccb + 4*j4] = g;
            }
            if (cq == kq) T[k*LDT + k] = pinv;   // identity-column trick
        }
        __syncthreads();
        const float f = (rg == k) ? 0.f : T[rg*LDT + k];
        __syncthreads();
        if (rg != k) {
            #pragma unroll
            for (int j4 = 0; j4 < 4; ++j4) {
                float4 own = *(float4*)&T[rg*LDT + ccb + 4*j4];
                const float4 pv = *(const float4*)&T[k*LDT + ccb + 4*j4];
                own.x -= f*pv.x; own.y -= f*pv.y; own.z -= f*pv.z; own.w -= f*pv.w;
                *(float4*)&T[rg*LDT + ccb + 4*j4] = own;
            }
            if (cq == kq) T[rg*LDT + k] -= f;    // blind gave f - f*pinv; want -f*pinv
        }
    }
    __syncthreads();
}

__global__ KATTR void gpm_setup(const float* __restrict__ mean0,
                                float* __restrict__ ginv0) {
    extern __shared__ float sm[];
    float* T = sm + AT_OFF;
    const int t = threadIdx.x;
    const int rg = t >> 3, cq = t & 7, ccb = cq << 4;
    const float* src = mean0 + rg*CC + ccb;
    #pragma unroll
    for (int j4 = 0; j4 < 4; ++j4)
        *(float4*)&T[rg*LDT + ccb + 4*j4] = *(const float4*)&src[4*j4];
    __syncthreads();
    ginv_inplace(sm, t);
    #pragma unroll
    for (int j4 = 0; j4 < 4; ++j4)
        *(float4*)&ginv0[rg*CC + ccb + 4*j4] = *(const float4*)&T[rg*LDT + ccb + 4*j4];
}

// 3-level shuffle (8-lane groups) then 1-in-8 lanes atomic into a scalar slot
#define SC_ADD(slot, val) { float v_ = (val);                                 \
    v_ += __shfl_xor(v_, 1, 64); v_ += __shfl_xor(v_, 2, 64);                 \
    v_ += __shfl_xor(v_, 4, 64);                                              \
    if ((l & 7) == 0) atomicAdd(&scal[slot], v_); }

__global__ KATTR void gpm_main(
        const float* __restrict__ zin, const float* __restrict__ mean0,
        const float* __restrict__ lvar, float* __restrict__ out,
        const float* __restrict__ ginv0, const int use_ws) {
    extern __shared__ float sm[];
    float* At  = sm + AT_OFF;
    float* U   = sm + U_OFF;
    float* vz  = sm + VEC(0);
    float* vaz = sm + VEC(1);
    float* vw0 = sm + VEC(2);   // becomes w after L5
    float* vt0 = sm + VEC(3);
    float* vvv = sm + VEC(4);
    float* vu1 = sm + VEC(5);   // pre-init az - SIG2*w0; becomes rr after L4
    float* vt2 = sm + VEC(6);   // pre-init z;            becomes dl after L6
    float* vuw = sm + VEC(7);
    float* vg1 = sm + VEC(8);
    float* vg2 = sm + VEC(9);
    float* scal = sm + SC_OFF;

    const int t = threadIdx.x, b = blockIdx.x;
    const int w = t >> 6, l = t & 63;
    const int r  = ((w & 1) << 6) | l;
    const int q  = w >> 1;
    const int cb = q << 4;

    // zero all vector slots (1280 floats) + scalar slots
    sm[VEC_BASE + t] = 0.f;
    if (t < 256) sm[VEC_BASE + 1024 + t] = 0.f;
    if (t < 24)  scal[t] = 0.f;

    const float pvar = expf(lvar[0]) + EPSV;

    float Areg[16], Greg[16];
    {
        const float* src = mean0 + r*CC + cb;
        #pragma unroll
        for (int j4 = 0; j4 < 4; ++j4) {
            const float4 v = *(const float4*)&src[4*j4];
            Areg[4*j4] = v.x; Areg[4*j4+1] = v.y; Areg[4*j4+2] = v.z; Areg[4*j4+3] = v.w;
        }
    }
    // U = pvar * I  (row r, cols [cb,cb+16))
    {
        const float4 z4 = {0.f, 0.f, 0.f, 0.f};
        #pragma unroll
        for (int j4 = 0; j4 < 4; ++j4)
            *(float4*)&U[r*LDT + cb + 4*j4] = z4;
        if (r >= cb && r < cb + 16) U[r*LDT + r] = pvar;
    }

    if (use_ws) {
        const float* src = ginv0 + r*CC + cb;
        #pragma unroll
        for (int j4 = 0; j4 < 4; ++j4) {
            const float4 v = *(const float4*)&src[4*j4];
            Greg[4*j4] = v.x; Greg[4*j4+1] = v.y; Greg[4*j4+2] = v.z; Greg[4*j4+3] = v.w;
        }
    } else {
        // fallback: stage A into At buffer, invert in place, read back
        #pragma unroll
        for (int j4 = 0; j4 < 4; ++j4) {
            float4 v; v.x = Areg[4*j4]; v.y = Areg[4*j4+1]; v.z = Areg[4*j4+2]; v.w = Areg[4*j4+3];
            *(float4*)&At[r*LDT + cb + 4*j4] = v;
        }
        __syncthreads();
        ginv_inplace(sm, t);
        #pragma unroll
        for (int j4 = 0; j4 < 4; ++j4) {
            const float4 v = *(const float4*)&At[r*LDT + cb + 4*j4];
            Greg[4*j4] = v.x; Greg[4*j4+1] = v.y; Greg[4*j4+2] = v.z; Greg[4*j4+3] = v.w;
        }
        __syncthreads();       // done reading Ginv before At is overwritten
    }
    // At = A^T (consecutive lanes -> consecutive addresses)
    #pragma unroll
    for (int j = 0; j < 16; ++j) At[(cb + j)*LDT + r] = Areg[j];
    if (t < 32)
        *(float4*)&vz[4*t] = *(const float4*)&zin[(size_t)b*CC + 4*t];
    __syncthreads();

    #pragma unroll 1
    for (int e = 0; e < EE; ++e) {
        // ---- L1: az = A z ; zero late accumulators (vuw,vg1,vg2) ; reset scalars ----
        {
            float s = 0.f;
            #pragma unroll
            for (int j4 = 0; j4 < 4; ++j4) {
                const float4 x = *(const float4*)&vz[cb + 4*j4];
                s += Areg[4*j4]*x.x + Areg[4*j4+1]*x.y + Areg[4*j4+2]*x.z + Areg[4*j4+3]*x.w;
            }
            atomicAdd(&vaz[r], s);
            if (t < 384) (sm + VEC(7))[t] = 0.f;       // vuw, vg1, vg2
            if (t == 512) { scal[0] = SIG2; scal[1] = 0.f; scal[2] = 0.f; scal[3] = 0.f; scal[4] = 0.f; }
        }
        __syncthreads();
        // ---- L2: w0 = Ginv az ----
        {
            float s = 0.f;
            #pragma unroll
            for (int j4 = 0; j4 < 4; ++j4) {
                const float4 x = *(const float4*)&vaz[cb + 4*j4];
                s += Greg[4*j4]*x.x + Greg[4*j4+1]*x.y + Greg[4*j4+2]*x.z + Greg[4*j4+3]*x.w;
            }
            atomicAdd(&vw0[r], s);
        }
        __syncthreads();
        // ---- L3: t0 = A^T w0 ; pre-init vu1 = az - SIG2*w0 ----
        {
            float s = 0.f;
            #pragma unroll
            for (int j4 = 0; j4 < 4; ++j4) {
                const float4 a = *(const float4*)&At[r*LDT + cb + 4*j4];
                const float4 x = *(const float4*)&vw0[cb + 4*j4];
                s += a.x*x.x + a.y*x.y + a.z*x.z + a.w*x.w;
            }
            atomicAdd(&vt0[r], s);
            if (t < 128) vu1[t] = vaz[t] - SIG2*vw0[t];
        }
        __syncthreads();
        // ---- L4: vu1 -= A t0   (after barrier: vu1 = rr = az - A A^T w0 - SIG2 w0) ----
        {
            float s = 0.f;
            #pragma unroll
            for (int j4 = 0; j4 < 4; ++j4) {
                const float4 x = *(const float4*)&vt0[cb + 4*j4];
                s += Areg[4*j4]*x.x + Areg[4*j4+1]*x.y + Areg[4*j4+2]*x.z + Areg[4*j4+3]*x.w;
            }
            atomicAdd(&vu1[r], -s);
        }
        __syncthreads();
        // ---- L5: vw0 += Ginv rr  (after barrier: vw0 = w) ; pre-init vt2 = z ----
        {
            float s = 0.f;
            #pragma unroll
            for (int j4 = 0; j4 < 4; ++j4) {
                const float4 x = *(const float4*)&vu1[cb + 4*j4];
                s += Greg[4*j4]*x.x + Greg[4*j4+1]*x.y + Greg[4*j4+2]*x.z + Greg[4*j4+3]*x.w;
            }
            atomicAdd(&vw0[r], s);
            if (t < 128) vt2[t] = vz[t];
        }
        __syncthreads();
        // ---- L6: vt2 -= A^T w (-> dl) ; uw = U w (U from LDS) ; sig partial ----
        {
            float s1 = 0.f, s2 = 0.f;
            #pragma unroll
            for (int j4 = 0; j4 < 4; ++j4) {
                const float4 a = *(const float4*)&At[r*LDT + cb + 4*j4];
                const float4 u = *(const float4*)&U[r*LDT + cb + 4*j4];
                const float4 x = *(const float4*)&vw0[cb + 4*j4];
                s1 += a.x*x.x + a.y*x.y + a.z*x.z + a.w*x.w;
                s2 += u.x*x.x + u.y*x.y + u.z*x.z + u.w*x.w;
            }
            atomicAdd(&vt2[r], -s1);
            atomicAdd(&vuw[r], s2);
            SC_ADD(0, s2 * vw0[r]);                    // sig partial
        }
        __syncthreads();
        // ---- L7: vv = A dl ; g2 = Ginv uw ; s_uwg2 ; d2 ----
        {
            float s1 = 0.f, s2 = 0.f;
            #pragma unroll
            for (int j4 = 0; j4 < 4; ++j4) {
                const float4 d4 = *(const float4*)&vt2[cb + 4*j4];
                const float4 u4 = *(const float4*)&vuw[cb + 4*j4];
                s1 += Areg[4*j4]*d4.x + Areg[4*j4+1]*d4.y + Areg[4*j4+2]*d4.z + Areg[4*j4+3]*d4.w;
                s2 += Greg[4*j4]*u4.x + Greg[4*j4+1]*u4.y + Greg[4*j4+2]*u4.z + Greg[4*j4+3]*u4.w;
            }
            atomicAdd(&vvv[r], s1);
            atomicAdd(&vg2[r], s2);
            SC_ADD(2, s2 * vuw[r]);                    // s_uwg2 partial
            if (t < 128) {
                float d_ = vt2[t]; d_ *= d_;
                d_ += __shfl_xor(d_, 1, 64); d_ += __shfl_xor(d_, 2, 64); d_ += __shfl_xor(d_, 4, 64);
                if ((l & 7) == 0) atomicAdd(&scal[1], d_);   // d2 partial
            }
        }
        __syncthreads();
        // ---- L8: g1 = Ginv vv ; s_vg1 ; s_uwg1 ----
        {
            float s = 0.f;
            #pragma unroll
            for (int j4 = 0; j4 < 4; ++j4) {
                const float4 x = *(const float4*)&vvv[cb + 4*j4];
                s += Greg[4*j4]*x.x + Greg[4*j4+1]*x.y + Greg[4*j4+2]*x.z + Greg[4*j4+3]*x.w;
            }
            atomicAdd(&vg1[r], s);
            SC_ADD(3, s * vvv[r]);                     // s_vg1 partial
            SC_ADD(4, s * vuw[r]);                     // s_uwg1 partial
        }
        __syncthreads();
        // ---- L9: rank updates of A (regs+At), Ginv (regs), U (LDS rmw) ----
        {
            const float sig = scal[0];
            const float inv_sig = 1.0f / sig;
            const float d2v = scal[1];
            const float s_uwg2 = scal[2], s_vg1 = scal[3], s_uwg1 = scal[4];
            // 2x2 Woodbury capacitance: G_new = G + v c^T + c v^T + d2 c c^T
            const float b11 = s_vg1 - d2v;
            const float b12 = 1.0f + s_uwg1*inv_sig;
            const float b22 = s_uwg2*inv_sig*inv_sig;
            const float idet = 1.0f / (b11*b22 - b12*b12);
            const float K11 = b22*idet, K12v = -b12*idet, K22 = b11*idet;
            const float k12s = K12v*inv_sig, k22s = K22*inv_sig*inv_sig;
            const float cr  = vuw[r]*inv_sig;
            const float g1r = vg1[r], g2r = vg2[r];
            const float ar_ = K11*g1r + k12s*g2r;
            const float br_ = k12s*g1r + k22s*g2r;
            #pragma unroll
            for (int j4 = 0; j4 < 4; ++j4) {
                const float4 dd = *(const float4*)&vt2[cb + 4*j4];
                Areg[4*j4]   += cr*dd.x; Areg[4*j4+1] += cr*dd.y;
                Areg[4*j4+2] += cr*dd.z; Areg[4*j4+3] += cr*dd.w;
                const float4 q1 = *(const float4*)&vg1[cb + 4*j4];
                const float4 q2 = *(const float4*)&vg2[cb + 4*j4];
                Greg[4*j4]   -= ar_*q1.x + br_*q2.x;
                Greg[4*j4+1] -= ar_*q1.y + br_*q2.y;
                Greg[4*j4+2] -= ar_*q1.z + br_*q2.z;
                Greg[4*j4+3] -= ar_*q1.w + br_*q2.w;
            }
            // U -= c uw^T (LDS rmw), separate window to cap register pressure
            #pragma unroll
            for (int j4 = 0; j4 < 4; ++j4) {
                const float4 uu = *(const float4*)&vuw[cb + 4*j4];
                float4 u = *(float4*)&U[r*LDT + cb + 4*j4];
                u.x -= cr*uu.x; u.y -= cr*uu.y; u.z -= cr*uu.z; u.w -= cr*uu.w;
                *(float4*)&U[r*LDT + cb + 4*j4] = u;
            }
            // write-through A^T
            #pragma unroll
            for (int j = 0; j < 16; ++j) At[(cb + j)*LDT + r] = Areg[j];
            // zero next step's early accumulators: vaz,vw0,vt0,vvv (VEC(1)..VEC(4))
            if (t < 512) (sm + VEC(1))[t] = 0.f;
            if (t < 32 && e + 1 < EE)
                *(float4*)&vz[4*t] = *(const float4*)&zin[((size_t)(e+1)*BB + b)*CC + 4*t];
        }
        __syncthreads();
    }

    // epilogue: post_mean from Areg
    {
        float* dst = out + (size_t)b*(MM*CC) + r*CC + cb;
        #pragma unroll
        for (int j4 = 0; j4 < 4; ++j4) {
            float4 v; v.x = Areg[4*j4]; v.y = Areg[4*j4+1]; v.z = Areg[4*j4+2]; v.w = Areg[4*j4+3];
            *(float4*)&dst[4*j4] = v;
        }
    }
    // post_cov from U (LDS)
    {
        float* dst = out + (size_t)BB*(MM*CC) + (size_t)b*(MM*MM) + r*MM + cb;
        #pragma unroll
        for (int j4 = 0; j4 < 4; ++j4)
            *(float4*)&dst[4*j4] = *(const float4*)&U[r*LDT + cb + 4*j4];
    }
    // dkl = mean_b[ C*sum(q/p) + sum((A-A0)^2)/p - C*M + C*sum(log p - log q) ]
    {
        const float inv_p = 1.0f / pvar;
        float acc = 0.f;
        const float* src = mean0 + r*CC + cb;
        #pragma unroll
        for (int j4 = 0; j4 < 4; ++j4) {
            const float4 a0 = *(const float4*)&src[4*j4];
            const float dx = Areg[4*j4]   - a0.x, dy = Areg[4*j4+1] - a0.y;
            const float dz = Areg[4*j4+2] - a0.z, dw = Areg[4*j4+3] - a0.w;
            acc += dx*dx + dy*dy + dz*dz + dw*dw;
        }
        float local = acc * inv_p;
        if (q == (r >> 4)) {   // owner of diagonal element of row r
            const float qd = U[r*LDT + r];
            local += (float)CC * (qd*inv_p + logf(pvar) - logf(qd));
        }
        #pragma unroll
        for (int m2 = 1; m2 < 64; m2 <<= 1) local += __shfl_xor(local, m2, 64);
        if (l == 0) scal[6 + w] = local;
        __syncthreads();
        if (t == 0) {
            float tot = 0.f;
            #pragma unroll
            for (int i = 0; i < 16; ++i) tot += scal[6 + i];
            tot -= (float)(CC*MM);
            atomicAdd(out + (size_t)2*BB*MM*CC, tot * (1.0f/(float)BB));
        }
    }
}

extern "C" void kernel_launch(void* const* d_in, const int* in_sizes, int n_in,
                              void* d_out, int out_size, void* d_ws, size_t ws_size,
                              hipStream_t stream) {
    (void)in_sizes; (void)n_in; (void)out_size;
    const float* zin   = (const float*)d_in[0];
    const float* mean0 = (const float*)d_in[1];
    const float* lvar  = (const float*)d_in[2];
    float* out = (float*)d_out;
    float* dkl = out + (size_t)2*BB*MM*CC;
    const int use_ws = (d_ws != nullptr && ws_size >= (size_t)MM*MM*4) ? 1 : 0;
    float* ginv0 = (float*)d_ws;

    hipFuncSetAttribute((const void*)gpm_setup, hipFuncAttributeMaxDynamicSharedMemorySize, SMEM_BYTES);
    hipFuncSetAttribute((const void*)gpm_main,  hipFuncAttributeMaxDynamicSharedMemorySize, SMEM_BYTES);

    hipMemsetAsync(dkl, 0, sizeof(float), stream);
    if (use_ws)
        gpm_setup<<<1, 1024, SMEM_BYTES, stream>>>(mean0, ginv0);
    gpm_main<<<BB, 1024, SMEM_BYTES, stream>>>(zin, mean0, lvar, out, ginv0, use_ws);
}

// Round 9
// 2431.043 us; speedup vs baseline: 1.5790x; 1.1308x over previous
//
#include <hip/hip_runtime.h>
#include <math.h>

// Problem constants (E,B,M,C) = (64, 512, 128, 128), sigma=0.5, eps=1e-6
#define MM   128
#define CC   128
#define EE   64
#define BB   512
#define LDT  132          // padded row stride for At in LDS
#define SIG2 0.25f
#define EPSV 1e-6f

// LDS layout (floats): At[128][132] + 10 vectors of 128 + 24 scalars = 72,800 B
// -> TWO blocks co-resident per CU (2 x 72.8 KB = 145.6 KB <= 160 KB): while
// one block sits in a barrier/latency bubble, the other's waves compute.
#define AT_OFF   0
#define VEC_BASE (128*LDT)
#define VEC(i)   (VEC_BASE + (i)*128)
// 0 vz, 1 vaz, 2 vw0(->w), 3 vt0, 4 vvv, 5 vu1(rr), 6 vt2(dl), 7 vuw, 8 vg1, 9 vg2
#define SC_OFF   (VEC_BASE + 10*128)
// scal: [0]=sig [1]=d2 [2]=s_uwg2 [3]=s_vg1 [4]=s_uwg1  [6..13]=epilogue wave sums [22]=GJ pivot
#define SMEM_FLOATS (SC_OFF + 24)
#define SMEM_BYTES  (SMEM_FLOATS * 4)     // 72,800 B

// ---------------------------------------------------------------------------
// 512 threads = 8 waves: w = t>>6, l = t&63
//   r = 64*(w&1)+l (row owned), q = w>>1 (0..3), cb = 32*q (column chunk)
// REGISTERS: Areg[32]+Ureg[32]+Greg[32] = 96 state. LDS: At + step vectors.
// ALLOCATOR LAW (r1-r8): VGPR budget = 256 / max_waves_per_eu.
//   waves_per_eu(2,2) -> 128 (r5-proven). It is a CODEGEN budget, not a
//   runtime occupancy cap: HW co-schedules 16 waves/CU at 128 VGPR (m69).
// ANTI-SPILL (r5 lesson: fused loops held 64-96 temps -> 3.4 GB scratch):
//   every matvec is windowed (<=4 float4 temps) with sched_barrier(0)
//   between windows; dual-operand phases split into two passes.
//   High-water ~ 96 state + 16 window + ~12 addr/scalars < 128.
// ---------------------------------------------------------------------------
#define KATTR __attribute__((amdgpu_flat_work_group_size(512, 512), amdgpu_waves_per_eu(2, 2)))

#define SB __builtin_amdgcn_sched_barrier(0)

// In-place Gauss-Jordan inverse of (A A^T + SIG2*I), 512 threads.
// A staged row-major in T=[128][LDT]; destroys T; leaves Ginv in T.
// Map: rg = t>>2, cq = t&3, ccb = 32*cq.   (verbatim from passing r5/r6)
__device__ __forceinline__ void ginv_inplace(float* sm, const int t) {
    float* T   = sm + AT_OFF;
    float* piv = sm + SC_OFF + 22;
    const int rg = t >> 2, cq = t & 3, ccb = cq << 5;
    float Gacc[32];
    #pragma unroll
    for (int j = 0; j < 32; ++j) Gacc[j] = 0.f;
    #pragma unroll 1
    for (int cc = 0; cc < 32; ++cc) {
        const float4 ar = *(const float4*)&T[rg*LDT + 4*cc];
        #pragma unroll
        for (int j = 0; j < 32; ++j) {
            const float4 br = *(const float4*)&T[(ccb + j)*LDT + 4*cc];
            Gacc[j] += ar.x*br.x + ar.y*br.y + ar.z*br.z + ar.w*br.w;
        }
    }
    #pragma unroll
    for (int j = 0; j < 32; ++j)
        if (ccb + j == rg) Gacc[j] += SIG2;
    __syncthreads();
    #pragma unroll
    for (int j4 = 0; j4 < 8; ++j4) {
        float4 v; v.x = Gacc[4*j4]; v.y = Gacc[4*j4+1]; v.z = Gacc[4*j4+2]; v.w = Gacc[4*j4+3];
        *(float4*)&T[rg*LDT + ccb + 4*j4] = v;
    }
    #pragma unroll 1
    for (int k = 0; k < 128; ++k) {
        const int kq = k >> 5;
        __syncthreads();
        if (rg == k && cq == kq) piv[0] = 1.0f / T[k*LDT + k];
        __syncthreads();
        if (rg == k) {
            const float pinv = piv[0];
            #pragma unroll
            for (int j4 = 0; j4 < 8; ++j4) {
                float4 g = *(float4*)&T[k*LDT + ccb + 4*j4];
                g.x *= pinv; g.y *= pinv; g.z *= pinv; g.w *= pinv;
                *(float4*)&T[k*LDT + ccb + 4*j4] = g;
            }
            if (cq == kq) T[k*LDT + k] = pinv;   // identity-column trick
        }
        __syncthreads();
        const float f = (rg == k) ? 0.f : T[rg*LDT + k];
        __syncthreads();
        if (rg != k) {
            #pragma unroll
            for (int j4 = 0; j4 < 8; ++j4) {
                float4 own = *(float4*)&T[rg*LDT + ccb + 4*j4];
                const float4 pv = *(const float4*)&T[k*LDT + ccb + 4*j4];
                own.x -= f*pv.x; own.y -= f*pv.y; own.z -= f*pv.z; own.w -= f*pv.w;
                *(float4*)&T[rg*LDT + ccb + 4*j4] = own;
            }
            if (cq == kq) T[rg*LDT + k] -= f;    // blind gave f - f*pinv; want -f*pinv
        }
    }
    __syncthreads();
}

__global__ KATTR void gpm_setup(const float* __restrict__ mean0,
                                float* __restrict__ ginv0) {
    extern __shared__ float sm[];
    float* T = sm + AT_OFF;
    const int t = threadIdx.x;
    const int rg = t >> 2, cq = t & 3, ccb = cq << 5;
    const float* src = mean0 + rg*CC + ccb;
    #pragma unroll
    for (int j4 = 0; j4 < 8; ++j4)
        *(float4*)&T[rg*LDT + ccb + 4*j4] = *(const float4*)&src[4*j4];
    __syncthreads();
    ginv_inplace(sm, t);
    #pragma unroll
    for (int j4 = 0; j4 < 8; ++j4)
        *(float4*)&ginv0[rg*CC + ccb + 4*j4] = *(const float4*)&T[rg*LDT + ccb + 4*j4];
}

// ---- pressure-capped matvec building blocks -------------------------------
// register-matrix half (16 cols): 4 float4 vector temps, static reg indices
#define RMVH(R, XV, OFF) { \
    const float4 x0_ = *(const float4*)&(XV)[cb + (OFF)]; \
    const float4 x1_ = *(const float4*)&(XV)[cb + (OFF) + 4]; \
    const float4 x2_ = *(const float4*)&(XV)[cb + (OFF) + 8]; \
    const float4 x3_ = *(const float4*)&(XV)[cb + (OFF) + 12]; \
    s_ += (R)[(OFF)+0]*x0_.x + (R)[(OFF)+1]*x0_.y + (R)[(OFF)+2]*x0_.z + (R)[(OFF)+3]*x0_.w \
        + (R)[(OFF)+4]*x1_.x + (R)[(OFF)+5]*x1_.y + (R)[(OFF)+6]*x1_.z + (R)[(OFF)+7]*x1_.w \
        + (R)[(OFF)+8]*x2_.x + (R)[(OFF)+9]*x2_.y + (R)[(OFF)+10]*x2_.z + (R)[(OFF)+11]*x2_.w \
        + (R)[(OFF)+12]*x3_.x + (R)[(OFF)+13]*x3_.y + (R)[(OFF)+14]*x3_.z + (R)[(OFF)+15]*x3_.w; }
#define RMV(R, XV) float s_ = 0.f; RMVH(R, XV, 0); SB; RMVH(R, XV, 16)

// LDS-matrix quarter (8 cols): 2+2 float4 temps
#define LMVQ(XV, OFF) { \
    const float4 a0_ = *(const float4*)&At[r*LDT + cb + (OFF)]; \
    const float4 a1_ = *(const float4*)&At[r*LDT + cb + (OFF) + 4]; \
    const float4 x0_ = *(const float4*)&(XV)[cb + (OFF)]; \
    const float4 x1_ = *(const float4*)&(XV)[cb + (OFF) + 4]; \
    s_ += a0_.x*x0_.x + a0_.y*x0_.y + a0_.z*x0_.z + a0_.w*x0_.w \
        + a1_.x*x1_.x + a1_.y*x1_.y + a1_.z*x1_.z + a1_.w*x1_.w; }
#define LMV(XV) float s_ = 0.f; LMVQ(XV, 0); SB; LMVQ(XV, 8); SB; LMVQ(XV, 16); SB; LMVQ(XV, 24)

// rank-1/2 update windows
#define AUPD(O) { \
    const float4 d0_ = *(const float4*)&vt2[cb+(O)];      \
    const float4 d1_ = *(const float4*)&vt2[cb+(O)+4];    \
    const float4 d2_ = *(const float4*)&vt2[cb+(O)+8];    \
    const float4 d3_ = *(const float4*)&vt2[cb+(O)+12];   \
    Areg[(O)+0]+=cr*d0_.x; Areg[(O)+1]+=cr*d0_.y; Areg[(O)+2]+=cr*d0_.z; Areg[(O)+3]+=cr*d0_.w; \
    Areg[(O)+4]+=cr*d1_.x; Areg[(O)+5]+=cr*d1_.y; Areg[(O)+6]+=cr*d1_.z; Areg[(O)+7]+=cr*d1_.w; \
    Areg[(O)+8]+=cr*d2_.x; Areg[(O)+9]+=cr*d2_.y; Areg[(O)+10]+=cr*d2_.z; Areg[(O)+11]+=cr*d2_.w; \
    Areg[(O)+12]+=cr*d3_.x; Areg[(O)+13]+=cr*d3_.y; Areg[(O)+14]+=cr*d3_.z; Areg[(O)+15]+=cr*d3_.w; }
#define UUPD(O) { \
    const float4 u0_ = *(const float4*)&vuw[cb+(O)];      \
    const float4 u1_ = *(const float4*)&vuw[cb+(O)+4];    \
    const float4 u2_ = *(const float4*)&vuw[cb+(O)+8];    \
    const float4 u3_ = *(const float4*)&vuw[cb+(O)+12];   \
    Ureg[(O)+0]-=cr*u0_.x; Ureg[(O)+1]-=cr*u0_.y; Ureg[(O)+2]-=cr*u0_.z; Ureg[(O)+3]-=cr*u0_.w; \
    Ureg[(O)+4]-=cr*u1_.x; Ureg[(O)+5]-=cr*u1_.y; Ureg[(O)+6]-=cr*u1_.z; Ureg[(O)+7]-=cr*u1_.w; \
    Ureg[(O)+8]-=cr*u2_.x; Ureg[(O)+9]-=cr*u2_.y; Ureg[(O)+10]-=cr*u2_.z; Ureg[(O)+11]-=cr*u2_.w; \
    Ureg[(O)+12]-=cr*u3_.x; Ureg[(O)+13]-=cr*u3_.y; Ureg[(O)+14]-=cr*u3_.z; Ureg[(O)+15]-=cr*u3_.w; }
#define GUPD(O) { \
    const float4 q10_ = *(const float4*)&vg1[cb+(O)];     \
    const float4 q11_ = *(const float4*)&vg1[cb+(O)+4];   \
    const float4 q20_ = *(const float4*)&vg2[cb+(O)];     \
    const float4 q21_ = *(const float4*)&vg2[cb+(O)+4];   \
    Greg[(O)+0] -= ar_*q10_.x + br_*q20_.x; Greg[(O)+1] -= ar_*q10_.y + br_*q20_.y; \
    Greg[(O)+2] -= ar_*q10_.z + br_*q20_.z; Greg[(O)+3] -= ar_*q10_.w + br_*q20_.w; \
    Greg[(O)+4] -= ar_*q11_.x + br_*q21_.x; Greg[(O)+5] -= ar_*q11_.y + br_*q21_.y; \
    Greg[(O)+6] -= ar_*q11_.z + br_*q21_.z; Greg[(O)+7] -= ar_*q11_.w + br_*q21_.w; }

// 3-level shuffle (8-lane groups) then 1-in-8 lanes atomic into a scalar slot
#define SC_ADD(slot, val) { float v_ = (val);                                 \
    v_ += __shfl_xor(v_, 1, 64); v_ += __shfl_xor(v_, 2, 64);                 \
    v_ += __shfl_xor(v_, 4, 64);                                              \
    if ((l & 7) == 0) atomicAdd(&scal[slot], v_); }

__global__ KATTR void gpm_main(
        const float* __restrict__ zin, const float* __restrict__ mean0,
        const float* __restrict__ lvar, float* __restrict__ out,
        const float* __restrict__ ginv0, const int use_ws) {
    extern __shared__ float sm[];
    float* At  = sm + AT_OFF;
    float* vz  = sm + VEC(0);
    float* vaz = sm + VEC(1);
    float* vw0 = sm + VEC(2);   // becomes w after L5
    float* vt0 = sm + VEC(3);
    float* vvv = sm + VEC(4);
    float* vu1 = sm + VEC(5);   // pre-init az - SIG2*w0; becomes rr after L4
    float* vt2 = sm + VEC(6);   // pre-init z;            becomes dl after L6
    float* vuw = sm + VEC(7);
    float* vg1 = sm + VEC(8);
    float* vg2 = sm + VEC(9);
    float* scal = sm + SC_OFF;

    const int t = threadIdx.x, b = blockIdx.x;
    const int w = t >> 6, l = t & 63;
    const int r  = ((w & 1) << 6) | l;
    const int q  = w >> 1;
    const int cb = q << 5;

    // zero all vector slots (1280 floats) + scalar slots
    sm[VEC_BASE + t] = 0.f;
    sm[VEC_BASE + 512 + t] = 0.f;
    if (t < 256) sm[VEC_BASE + 1024 + t] = 0.f;
    if (t < 24)  scal[t] = 0.f;

    const float pvar = expf(lvar[0]) + EPSV;

    float Areg[32], Ureg[32], Greg[32];

    if (use_ws) {
        const float* src = ginv0 + r*CC + cb;
        #pragma unroll
        for (int j4 = 0; j4 < 8; ++j4) {
            const float4 v = *(const float4*)&src[4*j4];
            Greg[4*j4] = v.x; Greg[4*j4+1] = v.y; Greg[4*j4+2] = v.z; Greg[4*j4+3] = v.w;
        }
    } else {
        // fallback: stage A into At buffer, invert in place, read back.
        // (Areg not yet live -> low pressure through ginv_inplace.)
        const float* src = mean0 + r*CC + cb;
        #pragma unroll
        for (int j4 = 0; j4 < 8; ++j4)
            *(float4*)&At[r*LDT + cb + 4*j4] = *(const float4*)&src[4*j4];
        __syncthreads();
        ginv_inplace(sm, t);
        #pragma unroll
        for (int j4 = 0; j4 < 8; ++j4) {
            const float4 v = *(const float4*)&At[r*LDT + cb + 4*j4];
            Greg[4*j4] = v.x; Greg[4*j4+1] = v.y; Greg[4*j4+2] = v.z; Greg[4*j4+3] = v.w;
        }
        __syncthreads();       // done reading Ginv before At is overwritten
    }
    {
        const float* src = mean0 + r*CC + cb;
        #pragma unroll
        for (int j4 = 0; j4 < 8; ++j4) {
            const float4 v = *(const float4*)&src[4*j4];
            Areg[4*j4] = v.x; Areg[4*j4+1] = v.y; Areg[4*j4+2] = v.z; Areg[4*j4+3] = v.w;
        }
    }
    #pragma unroll
    for (int j = 0; j < 32; ++j) Ureg[j] = (cb + j == r) ? pvar : 0.f;
    // At = A^T (consecutive lanes -> consecutive addresses)
    #pragma unroll
    for (int j = 0; j < 32; ++j) At[(cb + j)*LDT + r] = Areg[j];
    if (t < 32)
        *(float4*)&vz[4*t] = *(const float4*)&zin[(size_t)b*CC + 4*t];
    __syncthreads();

    #pragma unroll 1
    for (int e = 0; e < EE; ++e) {
        // ---- L1: az = A z ; zero late accumulators ; reset scalars ----
        {
            RMV(Areg, vz);
            atomicAdd(&vaz[r], s_);
            if (t < 384) (sm + VEC(7))[t] = 0.f;       // vuw, vg1, vg2
            if (t == 448) { scal[0] = SIG2; scal[1] = 0.f; scal[2] = 0.f; scal[3] = 0.f; scal[4] = 0.f; }
        }
        __syncthreads();
        // ---- L2: w0 = Ginv az ----
        {
            RMV(Greg, vaz);
            atomicAdd(&vw0[r], s_);
        }
        __syncthreads();
        // ---- L3: t0 = A^T w0 ; pre-init vu1 = az - SIG2*w0 ----
        {
            LMV(vw0);
            atomicAdd(&vt0[r], s_);
            if (t < 128) vu1[t] = vaz[t] - SIG2*vw0[t];
        }
        __syncthreads();
        // ---- L4: vu1 -= A t0  (-> rr = az - A A^T w0 - SIG2 w0) ----
        {
            RMV(Areg, vt0);
            atomicAdd(&vu1[r], -s_);
        }
        __syncthreads();
        // ---- L5: vw0 += Ginv rr  (-> w) ; pre-init vt2 = z ----
        {
            RMV(Greg, vu1);
            atomicAdd(&vw0[r], s_);
            if (t < 128) vt2[t] = vz[t];
        }
        __syncthreads();
        // ---- L6: vt2 -= A^T w (-> dl) ; uw = U w ; sig partial ----
        {
            {
                LMV(vw0);
                atomicAdd(&vt2[r], -s_);
            }
            {
                RMV(Ureg, vw0);
                atomicAdd(&vuw[r], s_);
                SC_ADD(0, s_ * vw0[r]);                // sig partial
            }
        }
        __syncthreads();
        // ---- L7: vv = A dl ; g2 = Ginv uw ; s_uwg2 ; d2 ----
        {
            {
                RMV(Areg, vt2);
                atomicAdd(&vvv[r], s_);
            }
            {
                RMV(Greg, vuw);
                atomicAdd(&vg2[r], s_);
                SC_ADD(2, s_ * vuw[r]);                // s_uwg2 partial
            }
            if (t < 128) {
                float d_ = vt2[t]; d_ *= d_;
                d_ += __shfl_xor(d_, 1, 64); d_ += __shfl_xor(d_, 2, 64); d_ += __shfl_xor(d_, 4, 64);
                if ((l & 7) == 0) atomicAdd(&scal[1], d_);   // d2 partial
            }
        }
        __syncthreads();
        // ---- L8: g1 = Ginv vv ; s_vg1 ; s_uwg1 ----
        {
            RMV(Greg, vvv);
            atomicAdd(&vg1[r], s_);
            SC_ADD(3, s_ * vvv[r]);                    // s_vg1 partial
            SC_ADD(4, s_ * vuw[r]);                    // s_uwg1 partial
        }
        __syncthreads();
        // ---- L9: rank updates of A (regs+At), U (regs), Ginv (regs) ----
        {
            const float sig = scal[0];
            const float inv_sig = 1.0f / sig;
            const float d2v = scal[1];
            const float s_uwg2 = scal[2], s_vg1 = scal[3], s_uwg1 = scal[4];
            // 2x2 Woodbury capacitance: G_new = G + v c^T + c v^T + d2 c c^T
            const float b11 = s_vg1 - d2v;
            const float b12 = 1.0f + s_uwg1*inv_sig;
            const float b22 = s_uwg2*inv_sig*inv_sig;
            const float idet = 1.0f / (b11*b22 - b12*b12);
            const float K11 = b22*idet, K12v = -b12*idet, K22 = b11*idet;
            const float k12s = K12v*inv_sig, k22s = K22*inv_sig*inv_sig;
            const float cr  = vuw[r]*inv_sig;
            const float g1r = vg1[r], g2r = vg2[r];
            const float ar_ = K11*g1r + k12s*g2r;
            const float br_ = k12s*g1r + k22s*g2r;
            AUPD(0); SB; AUPD(16); SB;
            // write-through A^T
            #pragma unroll
            for (int j = 0; j < 32; ++j) At[(cb + j)*LDT + r] = Areg[j];
            UUPD(0); SB; UUPD(16); SB;
            GUPD(0); SB; GUPD(8); SB; GUPD(16); SB; GUPD(24);
            // zero next step's early accumulators: vaz,vw0,vt0,vvv (VEC(1)..VEC(4))
            (sm + VEC(1))[t] = 0.f;
            if (t < 32 && e + 1 < EE)
                *(float4*)&vz[4*t] = *(const float4*)&zin[((size_t)(e+1)*BB + b)*CC + 4*t];
        }
        __syncthreads();
    }

    // epilogue: post_mean from Areg
    {
        float* dst = out + (size_t)b*(MM*CC) + r*CC + cb;
        #pragma unroll
        for (int j4 = 0; j4 < 8; ++j4) {
            float4 v; v.x = Areg[4*j4]; v.y = Areg[4*j4+1]; v.z = Areg[4*j4+2]; v.w = Areg[4*j4+3];
            *(float4*)&dst[4*j4] = v;
        }
    }
    // post_cov from Ureg + diag extraction (static indexing)
    float qd = 1.f;
    {
        float* dst = out + (size_t)BB*(MM*CC) + (size_t)b*(MM*MM) + r*MM + cb;
        #pragma unroll
        for (int j4 = 0; j4 < 8; ++j4) {
            float4 v; v.x = Ureg[4*j4]; v.y = Ureg[4*j4+1]; v.z = Ureg[4*j4+2]; v.w = Ureg[4*j4+3];
            *(float4*)&dst[4*j4] = v;
            if (cb + 4*j4     == r) qd = v.x;
            if (cb + 4*j4 + 1 == r) qd = v.y;
            if (cb + 4*j4 + 2 == r) qd = v.z;
            if (cb + 4*j4 + 3 == r) qd = v.w;
        }
    }
    // dkl = mean_b[ C*sum(q/p) + sum((A-A0)^2)/p - C*M + C*sum(log p - log q) ]
    {
        const float inv_p = 1.0f / pvar;
        float acc = 0.f;
        const float* src = mean0 + r*CC + cb;
        #pragma unroll
        for (int j4 = 0; j4 < 8; ++j4) {
            const float4 a0 = *(const float4*)&src[4*j4];
            const float dx = Areg[4*j4]   - a0.x, dy = Areg[4*j4+1] - a0.y;
            const float dz = Areg[4*j4+2] - a0.z, dw = Areg[4*j4+3] - a0.w;
            acc += dx*dx + dy*dy + dz*dz + dw*dw;
        }
        float local = acc * inv_p;
        if (q == (r >> 5))   // owner of diagonal element of row r
            local += (float)CC * (qd*inv_p + logf(pvar) - logf(qd));
        #pragma unroll
        for (int m2 = 1; m2 < 64; m2 <<= 1) local += __shfl_xor(local, m2, 64);
        if (l == 0) scal[6 + w] = local;
        __syncthreads();
        if (t == 0) {
            float tot = 0.f;
            #pragma unroll
            for (int i = 0; i < 8; ++i) tot += scal[6 + i];
            tot -= (float)(CC*MM);
            atomicAdd(out + (size_t)2*BB*MM*CC, tot * (1.0f/(float)BB));
        }
    }
}

extern "C" void kernel_launch(void* const* d_in, const int* in_sizes, int n_in,
                              void* d_out, int out_size, void* d_ws, size_t ws_size,
                              hipStream_t stream) {
    (void)in_sizes; (void)n_in; (void)out_size;
    const float* zin   = (const float*)d_in[0];
    const float* mean0 = (const float*)d_in[1];
    const float* lvar  = (const float*)d_in[2];
    float* out = (float*)d_out;
    float* dkl = out + (size_t)2*BB*MM*CC;
    const int use_ws = (d_ws != nullptr && ws_size >= (size_t)MM*MM*4) ? 1 : 0;
    float* ginv0 = (float*)d_ws;

    hipFuncSetAttribute((const void*)gpm_setup, hipFuncAttributeMaxDynamicSharedMemorySize, SMEM_BYTES);
    hipFuncSetAttribute((const void*)gpm_main,  hipFuncAttributeMaxDynamicSharedMemorySize, SMEM_BYTES);

    hipMemsetAsync(dkl, 0, sizeof(float), stream);
    if (use_ws)
        gpm_setup<<<1, 512, SMEM_BYTES, stream>>>(mean0, ginv0);
    gpm_main<<<BB, 512, SMEM_BYTES, stream>>>(zin, mean0, lvar, out, ginv0, use_ws);
}

// Round 10
// 1722.991 us; speedup vs baseline: 2.2279x; 1.4109x over previous
//
#include <hip/hip_runtime.h>
#include <math.h>

// Problem constants (E,B,M,C) = (64, 512, 128, 128), sigma=0.5, eps=1e-6
#define MM   128
#define CC   128
#define EE   64
#define BB   512
#define LDT  132          // padded row stride for At/U in LDS (b128 row reads measured conflict-free)
#define SIG2 0.25f
#define EPSV 1e-6f

// LDS layout (floats): At[128][132] + U[128][132] + 10 vectors of 128 + 24 scalars
#define AT_OFF   0
#define U_OFF    (128*LDT)
#define VEC_BASE (2*128*LDT)
#define VEC(i)   (VEC_BASE + (i)*128)
// vec order: 0 vz, 1 vaz, 2 vw0(->w), 3 vt0(unused), 4 vvv, 5 vu1(unused), 6 vt2(dl), 7 vuw, 8 vg1, 9 vg2
#define SC_OFF   (VEC_BASE + 10*128)
// scal: [0]=sig [1]=d2 [2]=s_uwg2 [3]=s_vg1 [4]=s_uwg1  [6..13]=epilogue wave sums [22]=GJ pivot
#define SMEM_FLOATS (SC_OFF + 24)
#define SMEM_BYTES  (SMEM_FLOATS * 4)    // 140,384 B -> 1 block/CU

// ---------------------------------------------------------------------------
// 512 threads = 8 waves: w = t>>6, l = t&63
//   r = 64*(w&1)+l (row owned), q = w>>1 (0..3), cb = 32*q (column chunk)
// REGISTERS: Areg[32] + Greg[32] = 64 state (~100 live).  U in LDS.
// This is the r6 no-spill champion config (512thr, waves_per_eu(1,2) -> 128
// VGPR budget, plain fused loops) with the ITERATIVE-REFINEMENT PHASES
// REMOVED: w = Ginv(Az) directly. The gram tracking is exact by construction
// (G_new = G + v c^T + c v^T + d2 c c^T with v = A*delta, d2 = |delta|^2
// computed from the ACTUAL A), so refinement only polished w's last digits.
// 9 -> 6 barrier phases/step, 10 -> 7 matvecs/step.
// NOTE: occupancy pins at 1 block/CU in ALL measured configs (r1-r9);
// phase count is the lever, not co-residency.
// ---------------------------------------------------------------------------
#define KATTR __attribute__((amdgpu_flat_work_group_size(512, 512), amdgpu_waves_per_eu(1, 2)))

// In-place Gauss-Jordan inverse of (A A^T + SIG2*I), 512 threads.
// A staged row-major in T=[128][LDT]; destroys T; leaves Ginv in T.
// Map: rg = t>>2, cq = t&3, ccb = 32*cq.   (verbatim from passing r5/r6/r9)
__device__ __forceinline__ void ginv_inplace(float* sm, const int t) {
    float* T   = sm + AT_OFF;
    float* piv = sm + SC_OFF + 22;
    const int rg = t >> 2, cq = t & 3, ccb = cq << 5;
    float Gacc[32];
    #pragma unroll
    for (int j = 0; j < 32; ++j) Gacc[j] = 0.f;
    #pragma unroll 1
    for (int cc = 0; cc < 32; ++cc) {
        const float4 ar = *(const float4*)&T[rg*LDT + 4*cc];
        #pragma unroll
        for (int j = 0; j < 32; ++j) {
            const float4 br = *(const float4*)&T[(ccb + j)*LDT + 4*cc];
            Gacc[j] += ar.x*br.x + ar.y*br.y + ar.z*br.z + ar.w*br.w;
        }
    }
    #pragma unroll
    for (int j = 0; j < 32; ++j)
        if (ccb + j == rg) Gacc[j] += SIG2;
    __syncthreads();
    #pragma unroll
    for (int j4 = 0; j4 < 8; ++j4) {
        float4 v; v.x = Gacc[4*j4]; v.y = Gacc[4*j4+1]; v.z = Gacc[4*j4+2]; v.w = Gacc[4*j4+3];
        *(float4*)&T[rg*LDT + ccb + 4*j4] = v;
    }
    #pragma unroll 1
    for (int k = 0; k < 128; ++k) {
        const int kq = k >> 5;
        __syncthreads();
        if (rg == k && cq == kq) piv[0] = 1.0f / T[k*LDT + k];
        __syncthreads();
        if (rg == k) {
            const float pinv = piv[0];
            #pragma unroll
            for (int j4 = 0; j4 < 8; ++j4) {
                float4 g = *(float4*)&T[k*LDT + ccb + 4*j4];
                g.x *= pinv; g.y *= pinv; g.z *= pinv; g.w *= pinv;
                *(float4*)&T[k*LDT + ccb + 4*j4] = g;
            }
            if (cq == kq) T[k*LDT + k] = pinv;   // identity-column trick
        }
        __syncthreads();
        const float f = (rg == k) ? 0.f : T[rg*LDT + k];
        __syncthreads();
        if (rg != k) {
            #pragma unroll
            for (int j4 = 0; j4 < 8; ++j4) {
                float4 own = *(float4*)&T[rg*LDT + ccb + 4*j4];
                const float4 pv = *(const float4*)&T[k*LDT + ccb + 4*j4];
                own.x -= f*pv.x; own.y -= f*pv.y; own.z -= f*pv.z; own.w -= f*pv.w;
                *(float4*)&T[rg*LDT + ccb + 4*j4] = own;
            }
            if (cq == kq) T[rg*LDT + k] -= f;    // blind gave f - f*pinv; want -f*pinv
        }
    }
    __syncthreads();
}

__global__ KATTR void gpm_setup(const float* __restrict__ mean0,
                                float* __restrict__ ginv0) {
    extern __shared__ float sm[];
    float* T = sm + AT_OFF;
    const int t = threadIdx.x;
    const int rg = t >> 2, cq = t & 3, ccb = cq << 5;
    const float* src = mean0 + rg*CC + ccb;
    #pragma unroll
    for (int j4 = 0; j4 < 8; ++j4)
        *(float4*)&T[rg*LDT + ccb + 4*j4] = *(const float4*)&src[4*j4];
    __syncthreads();
    ginv_inplace(sm, t);
    #pragma unroll
    for (int j4 = 0; j4 < 8; ++j4)
        *(float4*)&ginv0[rg*CC + ccb + 4*j4] = *(const float4*)&T[rg*LDT + ccb + 4*j4];
}

// 3-level shuffle (8-lane groups) then 1-in-8 lanes atomic into a scalar slot
#define SC_ADD(slot, val) { float v_ = (val);                                 \
    v_ += __shfl_xor(v_, 1, 64); v_ += __shfl_xor(v_, 2, 64);                 \
    v_ += __shfl_xor(v_, 4, 64);                                              \
    if ((l & 7) == 0) atomicAdd(&scal[slot], v_); }

__global__ KATTR void gpm_main(
        const float* __restrict__ zin, const float* __restrict__ mean0,
        const float* __restrict__ lvar, float* __restrict__ out,
        const float* __restrict__ ginv0, const int use_ws) {
    extern __shared__ float sm[];
    float* At  = sm + AT_OFF;
    float* U   = sm + U_OFF;
    float* vz  = sm + VEC(0);
    float* vaz = sm + VEC(1);
    float* vw0 = sm + VEC(2);   // w after P2
    float* vvv = sm + VEC(4);
    float* vt2 = sm + VEC(6);   // pre-init z in P2; becomes dl after P3
    float* vuw = sm + VEC(7);
    float* vg1 = sm + VEC(8);
    float* vg2 = sm + VEC(9);
    float* scal = sm + SC_OFF;

    const int t = threadIdx.x, b = blockIdx.x;
    const int w = t >> 6, l = t & 63;
    const int r  = ((w & 1) << 6) | l;
    const int q  = w >> 1;
    const int cb = q << 5;

    // zero accumulator vectors VEC(1)..VEC(9) (1152 floats) + scalar slots
    sm[VEC(1) + t] = 0.f;
    sm[VEC(1) + 512 + t] = 0.f;
    if (t < 128) sm[VEC(1) + 1024 + t] = 0.f;
    if (t < 24)  scal[t] = 0.f;

    const float pvar = expf(lvar[0]) + EPSV;

    float Areg[32], Greg[32];
    {
        const float* src = mean0 + r*CC + cb;
        #pragma unroll
        for (int j4 = 0; j4 < 8; ++j4) {
            const float4 v = *(const float4*)&src[4*j4];
            Areg[4*j4] = v.x; Areg[4*j4+1] = v.y; Areg[4*j4+2] = v.z; Areg[4*j4+3] = v.w;
        }
    }
    // U = pvar * I  (row r, cols [cb,cb+32))
    {
        const float4 z4 = {0.f, 0.f, 0.f, 0.f};
        #pragma unroll
        for (int j4 = 0; j4 < 8; ++j4)
            *(float4*)&U[r*LDT + cb + 4*j4] = z4;
        if (r >= cb && r < cb + 32) U[r*LDT + r] = pvar;
    }

    if (use_ws) {
        const float* src = ginv0 + r*CC + cb;
        #pragma unroll
        for (int j4 = 0; j4 < 8; ++j4) {
            const float4 v = *(const float4*)&src[4*j4];
            Greg[4*j4] = v.x; Greg[4*j4+1] = v.y; Greg[4*j4+2] = v.z; Greg[4*j4+3] = v.w;
        }
    } else {
        // fallback: stage A into At buffer, invert in place, read back
        #pragma unroll
        for (int j4 = 0; j4 < 8; ++j4) {
            float4 v; v.x = Areg[4*j4]; v.y = Areg[4*j4+1]; v.z = Areg[4*j4+2]; v.w = Areg[4*j4+3];
            *(float4*)&At[r*LDT + cb + 4*j4] = v;
        }
        __syncthreads();
        ginv_inplace(sm, t);
        #pragma unroll
        for (int j4 = 0; j4 < 8; ++j4) {
            const float4 v = *(const float4*)&At[r*LDT + cb + 4*j4];
            Greg[4*j4] = v.x; Greg[4*j4+1] = v.y; Greg[4*j4+2] = v.z; Greg[4*j4+3] = v.w;
        }
        __syncthreads();       // done reading Ginv before At is overwritten
    }
    // At = A^T (consecutive lanes -> consecutive addresses)
    #pragma unroll
    for (int j = 0; j < 32; ++j) At[(cb + j)*LDT + r] = Areg[j];
    if (t < 32)
        *(float4*)&vz[4*t] = *(const float4*)&zin[(size_t)b*CC + 4*t];
    __syncthreads();

    #pragma unroll 1
    for (int e = 0; e < EE; ++e) {
        // ---- P1: az = A z ; zero late accumulators (vuw,vg1,vg2) ; reset scalars ----
        {
            float s = 0.f;
            #pragma unroll
            for (int j4 = 0; j4 < 8; ++j4) {
                const float4 x = *(const float4*)&vz[cb + 4*j4];
                s += Areg[4*j4]*x.x + Areg[4*j4+1]*x.y + Areg[4*j4+2]*x.z + Areg[4*j4+3]*x.w;
            }
            atomicAdd(&vaz[r], s);
            if (t < 384) (sm + VEC(7))[t] = 0.f;       // vuw, vg1, vg2
            if (t == 448) { scal[0] = SIG2; scal[1] = 0.f; scal[2] = 0.f; scal[3] = 0.f; scal[4] = 0.f; }
        }
        __syncthreads();
        // ---- P2: w = Ginv az ; pre-init vt2 = z ----
        {
            float s = 0.f;
            #pragma unroll
            for (int j4 = 0; j4 < 8; ++j4) {
                const float4 x = *(const float4*)&vaz[cb + 4*j4];
                s += Greg[4*j4]*x.x + Greg[4*j4+1]*x.y + Greg[4*j4+2]*x.z + Greg[4*j4+3]*x.w;
            }
            atomicAdd(&vw0[r], s);
            if (t < 128) vt2[t] = vz[t];
        }
        __syncthreads();
        // ---- P3: vt2 -= A^T w (-> dl) ; uw = U w ; sig partial ----
        {
            float s1 = 0.f, s2 = 0.f;
            #pragma unroll
            for (int j4 = 0; j4 < 8; ++j4) {
                const float4 a = *(const float4*)&At[r*LDT + cb + 4*j4];
                const float4 u = *(const float4*)&U[r*LDT + cb + 4*j4];
                const float4 x = *(const float4*)&vw0[cb + 4*j4];
                s1 += a.x*x.x + a.y*x.y + a.z*x.z + a.w*x.w;
                s2 += u.x*x.x + u.y*x.y + u.z*x.z + u.w*x.w;
            }
            atomicAdd(&vt2[r], -s1);
            atomicAdd(&vuw[r], s2);
            SC_ADD(0, s2 * vw0[r]);                    // sig partial
        }
        __syncthreads();
        // ---- P4: vv = A dl ; g2 = Ginv uw ; s_uwg2 ; d2 ----
        {
            float s1 = 0.f, s2 = 0.f;
            #pragma unroll
            for (int j4 = 0; j4 < 8; ++j4) {
                const float4 d4 = *(const float4*)&vt2[cb + 4*j4];
                const float4 u4 = *(const float4*)&vuw[cb + 4*j4];
                s1 += Areg[4*j4]*d4.x + Areg[4*j4+1]*d4.y + Areg[4*j4+2]*d4.z + Areg[4*j4+3]*d4.w;
                s2 += Greg[4*j4]*u4.x + Greg[4*j4+1]*u4.y + Greg[4*j4+2]*u4.z + Greg[4*j4+3]*u4.w;
            }
            atomicAdd(&vvv[r], s1);
            atomicAdd(&vg2[r], s2);
            SC_ADD(2, s2 * vuw[r]);                    // s_uwg2 partial
            if (t < 128) {
                float d_ = vt2[t]; d_ *= d_;
                d_ += __shfl_xor(d_, 1, 64); d_ += __shfl_xor(d_, 2, 64); d_ += __shfl_xor(d_, 4, 64);
                if ((l & 7) == 0) atomicAdd(&scal[1], d_);   // d2 partial
            }
        }
        __syncthreads();
        // ---- P5: g1 = Ginv vv ; s_vg1 ; s_uwg1 ----
        {
            float s = 0.f;
            #pragma unroll
            for (int j4 = 0; j4 < 8; ++j4) {
                const float4 x = *(const float4*)&vvv[cb + 4*j4];
                s += Greg[4*j4]*x.x + Greg[4*j4+1]*x.y + Greg[4*j4+2]*x.z + Greg[4*j4+3]*x.w;
            }
            atomicAdd(&vg1[r], s);
            SC_ADD(3, s * vvv[r]);                     // s_vg1 partial
            SC_ADD(4, s * vuw[r]);                     // s_uwg1 partial
        }
        __syncthreads();
        // ---- P6: rank updates of A (regs+At), U (LDS rmw), Ginv (regs) ----
        {
            const float sig = scal[0];
            const float inv_sig = 1.0f / sig;
            const float d2v = scal[1];
            const float s_uwg2 = scal[2], s_vg1 = scal[3], s_uwg1 = scal[4];
            // 2x2 Woodbury capacitance: G_new = G + v c^T + c v^T + d2 c c^T
            const float b11 = s_vg1 - d2v;
            const float b12 = 1.0f + s_uwg1*inv_sig;
            const float b22 = s_uwg2*inv_sig*inv_sig;
            const float idet = 1.0f / (b11*b22 - b12*b12);
            const float K11 = b22*idet, K12v = -b12*idet, K22 = b11*idet;
            const float k12s = K12v*inv_sig, k22s = K22*inv_sig*inv_sig;
            const float cr  = vuw[r]*inv_sig;
            const float g1r = vg1[r], g2r = vg2[r];
            const float ar_ = K11*g1r + k12s*g2r;
            const float br_ = k12s*g1r + k22s*g2r;
            // A += c dl^T (regs)
            #pragma unroll
            for (int j4 = 0; j4 < 8; ++j4) {
                const float4 dd = *(const float4*)&vt2[cb + 4*j4];
                Areg[4*j4]   += cr*dd.x; Areg[4*j4+1] += cr*dd.y;
                Areg[4*j4+2] += cr*dd.z; Areg[4*j4+3] += cr*dd.w;
            }
            // U -= c uw^T (LDS rmw)
            #pragma unroll
            for (int j4 = 0; j4 < 8; ++j4) {
                const float4 uu = *(const float4*)&vuw[cb + 4*j4];
                float4 u = *(float4*)&U[r*LDT + cb + 4*j4];
                u.x -= cr*uu.x; u.y -= cr*uu.y; u.z -= cr*uu.z; u.w -= cr*uu.w;
                *(float4*)&U[r*LDT + cb + 4*j4] = u;
            }
            // Ginv -= [g1 g2s] K [g1 g2s]^T (regs)
            #pragma unroll
            for (int j4 = 0; j4 < 8; ++j4) {
                const float4 q1 = *(const float4*)&vg1[cb + 4*j4];
                const float4 q2 = *(const float4*)&vg2[cb + 4*j4];
                Greg[4*j4]   -= ar_*q1.x + br_*q2.x;
                Greg[4*j4+1] -= ar_*q1.y + br_*q2.y;
                Greg[4*j4+2] -= ar_*q1.z + br_*q2.z;
                Greg[4*j4+3] -= ar_*q1.w + br_*q2.w;
            }
            // write-through A^T
            #pragma unroll
            for (int j = 0; j < 32; ++j) At[(cb + j)*LDT + r] = Areg[j];
            // zero next step's early accumulators: vaz,vw0,vt0,vvv (VEC(1)..VEC(4))
            (sm + VEC(1))[t] = 0.f;
            if (t < 32 && e + 1 < EE)
                *(float4*)&vz[4*t] = *(const float4*)&zin[((size_t)(e+1)*BB + b)*CC + 4*t];
        }
        __syncthreads();
    }

    // epilogue: post_mean from Areg
    {
        float* dst = out + (size_t)b*(MM*CC) + r*CC + cb;
        #pragma unroll
        for (int j4 = 0; j4 < 8; ++j4) {
            float4 v; v.x = Areg[4*j4]; v.y = Areg[4*j4+1]; v.z = Areg[4*j4+2]; v.w = Areg[4*j4+3];
            *(float4*)&dst[4*j4] = v;
        }
    }
    // post_cov from U (LDS)
    {
        float* dst = out + (size_t)BB*(MM*CC) + (size_t)b*(MM*MM) + r*MM + cb;
        #pragma unroll
        for (int j4 = 0; j4 < 8; ++j4)
            *(float4*)&dst[4*j4] = *(const float4*)&U[r*LDT + cb + 4*j4];
    }
    // dkl = mean_b[ C*sum(q/p) + sum((A-A0)^2)/p - C*M + C*sum(log p - log q) ]
    {
        const float inv_p = 1.0f / pvar;
        float acc = 0.f;
        const float* src = mean0 + r*CC + cb;
        #pragma unroll
        for (int j4 = 0; j4 < 8; ++j4) {
            const float4 a0 = *(const float4*)&src[4*j4];
            const float dx = Areg[4*j4]   - a0.x, dy = Areg[4*j4+1] - a0.y;
            const float dz = Areg[4*j4+2] - a0.z, dw = Areg[4*j4+3] - a0.w;
            acc += dx*dx + dy*dy + dz*dz + dw*dw;
        }
        float local = acc * inv_p;
        if (q == (r >> 5)) {   // owner of diagonal element of row r
            const float qd = U[r*LDT + r];
            local += (float)CC * (qd*inv_p + logf(pvar) - logf(qd));
        }
        #pragma unroll
        for (int m2 = 1; m2 < 64; m2 <<= 1) local += __shfl_xor(local, m2, 64);
        if (l == 0) scal[6 + w] = local;
        __syncthreads();
        if (t == 0) {
            float tot = 0.f;
            #pragma unroll
            for (int i = 0; i < 8; ++i) tot += scal[6 + i];
            tot -= (float)(CC*MM);
            atomicAdd(out + (size_t)2*BB*MM*CC, tot * (1.0f/(float)BB));
        }
    }
}

extern "C" void kernel_launch(void* const* d_in, const int* in_sizes, int n_in,
                              void* d_out, int out_size, void* d_ws, size_t ws_size,
                              hipStream_t stream) {
    (void)in_sizes; (void)n_in; (void)out_size;
    const float* zin   = (const float*)d_in[0];
    const float* mean0 = (const float*)d_in[1];
    const float* lvar  = (const float*)d_in[2];
    float* out = (float*)d_out;
    float* dkl = out + (size_t)2*BB*MM*CC;
    const int use_ws = (d_ws != nullptr && ws_size >= (size_t)MM*MM*4) ? 1 : 0;
    float* ginv0 = (float*)d_ws;

    hipFuncSetAttribute((const void*)gpm_setup, hipFuncAttributeMaxDynamicSharedMemorySize, SMEM_BYTES);
    hipFuncSetAttribute((const void*)gpm_main,  hipFuncAttributeMaxDynamicSharedMemorySize, SMEM_BYTES);

    hipMemsetAsync(dkl, 0, sizeof(float), stream);
    if (use_ws)
        gpm_setup<<<1, 512, SMEM_BYTES, stream>>>(mean0, ginv0);
    gpm_main<<<BB, 512, SMEM_BYTES, stream>>>(zin, mean0, lvar, out, ginv0, use_ws);
}

// Round 11
// 1464.673 us; speedup vs baseline: 2.6208x; 1.1764x over previous
//
#include <hip/hip_runtime.h>
#include <math.h>

// Problem constants (E,B,M,C) = (64, 512, 128, 128), sigma=0.5, eps=1e-6
#define MM   128
#define CC   128
#define EE   64
#define BB   512
#define LDT  132          // padded row stride for At/U in LDS (measured conflict-free r4-r10)
#define SIG2 0.25f
#define SIG4 0.0625f
#define EPSV 1e-6f

// LDS layout (floats): At[128][132] + U[128][132] + 7 vectors of 128 + 24 scalars
#define AT_OFF   0
#define U_OFF    (128*LDT)
#define VEC_BASE (2*128*LDT)
#define VEC(i)   (VEC_BASE + (i)*128)
// vec: 0 vz, 1 vaz, 2 vw0(w), 3 vt2(z->dl), 4 vuw, 5 vg1(=Ginv w), 6 vg2
#define SC_OFF   (VEC_BASE + 7*128)
// scal: [0]=sig [1]=d2 [2]=s_uwg2 [3]=s_vg1/SIG4 [4]=s_uwg1/SIG2
//       [6..13]=epilogue wave sums [22]=GJ pivot
#define SMEM_FLOATS (SC_OFF + 24)
#define SMEM_BYTES  (SMEM_FLOATS * 4)    // 138,848 B -> 1 block/CU

// ---------------------------------------------------------------------------
// 512 threads = 8 waves: w = t>>6, l = t&63
//   r = 64*(w&1)+l (row owned), q = w>>1 (0..3), cb = 32*q (column chunk)
// REGISTERS: Areg[32] + Greg[32] = 64 state (~100 live). U in LDS.
// 4-PHASE SCHEDULE (r10 measured: time ∝ phase count; 9ph=2218, 6ph=1501):
//   P2: w = Ginv az            ; vt2=z ; zero vuw/vg1/vg2 ; reset scalars
//   P3: dl=z-At w ; uw=U w ; g1c=Ginv w ; sig,s_vg1 partials ; zero vaz
//   P4: g2=Ginv uw ; d2 ; s_uwg1 ; s_uwg2 ; prefetch z_next ; zero vw0
//   P5: Woodbury K ; update A,U,Ginv ; At write ; az_next = A_new z_next
// Key identity: v = A*delta = az - G w + SIG2 w ~= SIG2*w (solve residual
// ~1e-6 rel; r10 proved drift is below the bf16 output-compare floor), so
// g1 = Ginv v = SIG2*g1c computed IN P3 (shares the w-vector load with
// At w and U w). Scales folded: s_vg1 = SIG4*acc, s_uwg1 = SIG2*acc,
// g1r = SIG2*vg1[r], Greg -= (ar_*SIG2)*vg1 + br_*vg2.
// ---------------------------------------------------------------------------
#define KATTR __attribute__((amdgpu_flat_work_group_size(512, 512), amdgpu_waves_per_eu(1, 2)))

// In-place Gauss-Jordan inverse of (A A^T + SIG2*I), 512 threads.
// A staged row-major in T=[128][LDT]; destroys T; leaves Ginv in T.
// Map: rg = t>>2, cq = t&3, ccb = 32*cq.   (verbatim from passing r5-r10)
__device__ __forceinline__ void ginv_inplace(float* sm, const int t) {
    float* T   = sm + AT_OFF;
    float* piv = sm + SC_OFF + 22;
    const int rg = t >> 2, cq = t & 3, ccb = cq << 5;
    float Gacc[32];
    #pragma unroll
    for (int j = 0; j < 32; ++j) Gacc[j] = 0.f;
    #pragma unroll 1
    for (int cc = 0; cc < 32; ++cc) {
        const float4 ar = *(const float4*)&T[rg*LDT + 4*cc];
        #pragma unroll
        for (int j = 0; j < 32; ++j) {
            const float4 br = *(const float4*)&T[(ccb + j)*LDT + 4*cc];
            Gacc[j] += ar.x*br.x + ar.y*br.y + ar.z*br.z + ar.w*br.w;
        }
    }
    #pragma unroll
    for (int j = 0; j < 32; ++j)
        if (ccb + j == rg) Gacc[j] += SIG2;
    __syncthreads();
    #pragma unroll
    for (int j4 = 0; j4 < 8; ++j4) {
        float4 v; v.x = Gacc[4*j4]; v.y = Gacc[4*j4+1]; v.z = Gacc[4*j4+2]; v.w = Gacc[4*j4+3];
        *(float4*)&T[rg*LDT + ccb + 4*j4] = v;
    }
    #pragma unroll 1
    for (int k = 0; k < 128; ++k) {
        const int kq = k >> 5;
        __syncthreads();
        if (rg == k && cq == kq) piv[0] = 1.0f / T[k*LDT + k];
        __syncthreads();
        if (rg == k) {
            const float pinv = piv[0];
            #pragma unroll
            for (int j4 = 0; j4 < 8; ++j4) {
                float4 g = *(float4*)&T[k*LDT + ccb + 4*j4];
                g.x *= pinv; g.y *= pinv; g.z *= pinv; g.w *= pinv;
                *(float4*)&T[k*LDT + ccb + 4*j4] = g;
            }
            if (cq == kq) T[k*LDT + k] = pinv;   // identity-column trick
        }
        __syncthreads();
        const float f = (rg == k) ? 0.f : T[rg*LDT + k];
        __syncthreads();
        if (rg != k) {
            #pragma unroll
            for (int j4 = 0; j4 < 8; ++j4) {
                float4 own = *(float4*)&T[rg*LDT + ccb + 4*j4];
                const float4 pv = *(const float4*)&T[k*LDT + ccb + 4*j4];
                own.x -= f*pv.x; own.y -= f*pv.y; own.z -= f*pv.z; own.w -= f*pv.w;
                *(float4*)&T[rg*LDT + ccb + 4*j4] = own;
            }
            if (cq == kq) T[rg*LDT + k] -= f;    // blind gave f - f*pinv; want -f*pinv
        }
    }
    __syncthreads();
}

__global__ KATTR void gpm_setup(const float* __restrict__ mean0,
                                float* __restrict__ ginv0) {
    extern __shared__ float sm[];
    float* T = sm + AT_OFF;
    const int t = threadIdx.x;
    const int rg = t >> 2, cq = t & 3, ccb = cq << 5;
    const float* src = mean0 + rg*CC + ccb;
    #pragma unroll
    for (int j4 = 0; j4 < 8; ++j4)
        *(float4*)&T[rg*LDT + ccb + 4*j4] = *(const float4*)&src[4*j4];
    __syncthreads();
    ginv_inplace(sm, t);
    #pragma unroll
    for (int j4 = 0; j4 < 8; ++j4)
        *(float4*)&ginv0[rg*CC + ccb + 4*j4] = *(const float4*)&T[rg*LDT + ccb + 4*j4];
}

// 3-level shuffle (8-lane groups) then 1-in-8 lanes atomic into a scalar slot
#define SC_ADD(slot, val) { float v_ = (val);                                 \
    v_ += __shfl_xor(v_, 1, 64); v_ += __shfl_xor(v_, 2, 64);                 \
    v_ += __shfl_xor(v_, 4, 64);                                              \
    if ((l & 7) == 0) atomicAdd(&scal[slot], v_); }

__global__ KATTR void gpm_main(
        const float* __restrict__ zin, const float* __restrict__ mean0,
        const float* __restrict__ lvar, float* __restrict__ out,
        const float* __restrict__ ginv0, const int use_ws) {
    extern __shared__ float sm[];
    float* At  = sm + AT_OFF;
    float* U   = sm + U_OFF;
    float* vz  = sm + VEC(0);
    float* vaz = sm + VEC(1);
    float* vw0 = sm + VEC(2);
    float* vt2 = sm + VEC(3);   // pre-init z in P2; dl after P3
    float* vuw = sm + VEC(4);
    float* vg1 = sm + VEC(5);   // holds g1c = Ginv w (true g1 = SIG2*g1c)
    float* vg2 = sm + VEC(6);
    float* scal = sm + SC_OFF;

    const int t = threadIdx.x, b = blockIdx.x;
    const int w = t >> 6, l = t & 63;
    const int r  = ((w & 1) << 6) | l;
    const int q  = w >> 1;
    const int cb = q << 5;

    // zero accumulator vectors VEC(1)..VEC(6) (768 floats) + scalar slots
    sm[VEC(1) + t] = 0.f;
    if (t < 256) sm[VEC(1) + 512 + t] = 0.f;
    if (t < 24)  scal[t] = 0.f;

    const float pvar = expf(lvar[0]) + EPSV;

    float Areg[32], Greg[32];

    if (use_ws) {
        const float* src = ginv0 + r*CC + cb;
        #pragma unroll
        for (int j4 = 0; j4 < 8; ++j4) {
            const float4 v = *(const float4*)&src[4*j4];
            Greg[4*j4] = v.x; Greg[4*j4+1] = v.y; Greg[4*j4+2] = v.z; Greg[4*j4+3] = v.w;
        }
    } else {
        // fallback: stage A into At buffer, invert in place, read back
        const float* src = mean0 + r*CC + cb;
        #pragma unroll
        for (int j4 = 0; j4 < 8; ++j4)
            *(float4*)&At[r*LDT + cb + 4*j4] = *(const float4*)&src[4*j4];
        __syncthreads();
        ginv_inplace(sm, t);
        #pragma unroll
        for (int j4 = 0; j4 < 8; ++j4) {
            const float4 v = *(const float4*)&At[r*LDT + cb + 4*j4];
            Greg[4*j4] = v.x; Greg[4*j4+1] = v.y; Greg[4*j4+2] = v.z; Greg[4*j4+3] = v.w;
        }
        __syncthreads();       // done reading Ginv before At is overwritten
    }
    {
        const float* src = mean0 + r*CC + cb;
        #pragma unroll
        for (int j4 = 0; j4 < 8; ++j4) {
            const float4 v = *(const float4*)&src[4*j4];
            Areg[4*j4] = v.x; Areg[4*j4+1] = v.y; Areg[4*j4+2] = v.z; Areg[4*j4+3] = v.w;
        }
    }
    // U = pvar * I  (row r, cols [cb,cb+32))
    {
        const float4 z4 = {0.f, 0.f, 0.f, 0.f};
        #pragma unroll
        for (int j4 = 0; j4 < 8; ++j4)
            *(float4*)&U[r*LDT + cb + 4*j4] = z4;
        if (r >= cb && r < cb + 32) U[r*LDT + r] = pvar;
    }
    // At = A^T (consecutive lanes -> consecutive addresses)
    #pragma unroll
    for (int j = 0; j < 32; ++j) At[(cb + j)*LDT + r] = Areg[j];
    if (t < 32)
        *(float4*)&vz[4*t] = *(const float4*)&zin[(size_t)b*CC + 4*t];
    __syncthreads();

    // P0 (prologue): az(0) = A z0
    {
        float s = 0.f;
        #pragma unroll
        for (int j4 = 0; j4 < 8; ++j4) {
            const float4 x = *(const float4*)&vz[cb + 4*j4];
            s += Areg[4*j4]*x.x + Areg[4*j4+1]*x.y + Areg[4*j4+2]*x.z + Areg[4*j4+3]*x.w;
        }
        atomicAdd(&vaz[r], s);
    }
    __syncthreads();

    #pragma unroll 1
    for (int e = 0; e < EE; ++e) {
        // ---- P2: w = Ginv az ; vt2 = z ; zero vuw/vg1/vg2 ; reset scalars ----
        {
            float s = 0.f;
            #pragma unroll
            for (int j4 = 0; j4 < 8; ++j4) {
                const float4 x = *(const float4*)&vaz[cb + 4*j4];
                s += Greg[4*j4]*x.x + Greg[4*j4+1]*x.y + Greg[4*j4+2]*x.z + Greg[4*j4+3]*x.w;
            }
            atomicAdd(&vw0[r], s);
            if (t < 128) vt2[t] = vz[t];
            if (t < 384) (sm + VEC(4))[t] = 0.f;       // vuw, vg1, vg2
            if (t == 448) { scal[0] = SIG2; scal[1] = 0.f; scal[2] = 0.f; scal[3] = 0.f; scal[4] = 0.f; }
        }
        __syncthreads();
        // ---- P3: dl = z - At w ; uw = U w ; g1c = Ginv w ; sig, s_vg1 ; zero vaz ----
        {
            float s1 = 0.f, s2 = 0.f, s3 = 0.f;
            #pragma unroll
            for (int j4 = 0; j4 < 8; ++j4) {
                const float4 a = *(const float4*)&At[r*LDT + cb + 4*j4];
                const float4 u = *(const float4*)&U[r*LDT + cb + 4*j4];
                const float4 x = *(const float4*)&vw0[cb + 4*j4];
                s1 += a.x*x.x + a.y*x.y + a.z*x.z + a.w*x.w;
                s2 += u.x*x.x + u.y*x.y + u.z*x.z + u.w*x.w;
                s3 += Greg[4*j4]*x.x + Greg[4*j4+1]*x.y + Greg[4*j4+2]*x.z + Greg[4*j4+3]*x.w;
            }
            atomicAdd(&vt2[r], -s1);
            atomicAdd(&vuw[r], s2);
            atomicAdd(&vg1[r], s3);
            const float w_r = vw0[r];
            SC_ADD(0, s2 * w_r);                       // sig partial (wT U w)
            SC_ADD(3, s3 * w_r);                       // s_vg1 / SIG4 partial (wT Ginv w)
            if (t < 128) vaz[t] = 0.f;
        }
        __syncthreads();
        // ---- P4: g2 = Ginv uw ; s_uwg2 ; d2 ; s_uwg1 ; prefetch z ; zero vw0 ----
        {
            float s = 0.f;
            #pragma unroll
            for (int j4 = 0; j4 < 8; ++j4) {
                const float4 x = *(const float4*)&vuw[cb + 4*j4];
                s += Greg[4*j4]*x.x + Greg[4*j4+1]*x.y + Greg[4*j4+2]*x.z + Greg[4*j4+3]*x.w;
            }
            atomicAdd(&vg2[r], s);
            SC_ADD(2, s * vuw[r]);                     // s_uwg2 partial
            if (t < 128) {
                float d_ = vt2[t]; d_ *= d_;
                d_ += __shfl_xor(d_, 1, 64); d_ += __shfl_xor(d_, 2, 64); d_ += __shfl_xor(d_, 4, 64);
                if ((l & 7) == 0) atomicAdd(&scal[1], d_);   // d2
                float p_ = vg1[t] * vuw[t];
                p_ += __shfl_xor(p_, 1, 64); p_ += __shfl_xor(p_, 2, 64); p_ += __shfl_xor(p_, 4, 64);
                if ((l & 7) == 0) atomicAdd(&scal[4], p_);   // s_uwg1 / SIG2
                vw0[t] = 0.f;
            }
            if (t < 32 && e + 1 < EE)
                *(float4*)&vz[4*t] = *(const float4*)&zin[((size_t)(e+1)*BB + b)*CC + 4*t];
        }
        __syncthreads();
        // ---- P5: Woodbury K ; update A (regs+At), U (LDS), Ginv (regs) ; az_next ----
        {
            const float sig = scal[0];
            const float inv_sig = 1.0f / sig;
            const float d2v = scal[1];
            const float s_uwg2 = scal[2];
            const float s_vg1  = SIG4 * scal[3];
            const float s_uwg1 = SIG2 * scal[4];
            // 2x2 Woodbury capacitance: G_new = G + v c^T + c v^T + d2 c c^T, v = SIG2*w
            const float b11 = s_vg1 - d2v;
            const float b12 = 1.0f + s_uwg1*inv_sig;
            const float b22 = s_uwg2*inv_sig*inv_sig;
            const float idet = 1.0f / (b11*b22 - b12*b12);
            const float K11 = b22*idet, K12v = -b12*idet, K22 = b11*idet;
            const float k12s = K12v*inv_sig, k22s = K22*inv_sig*inv_sig;
            const float cr  = vuw[r]*inv_sig;
            const float g1r = SIG2 * vg1[r];
            const float g2r = vg2[r];
            const float ar_ = K11*g1r + k12s*g2r;
            const float br_ = k12s*g1r + k22s*g2r;
            const float ars = ar_ * SIG2;              // fold true-g1 scale into coeff
            #pragma unroll
            for (int j4 = 0; j4 < 8; ++j4) {
                const float4 dd = *(const float4*)&vt2[cb + 4*j4];
                Areg[4*j4]   += cr*dd.x; Areg[4*j4+1] += cr*dd.y;
                Areg[4*j4+2] += cr*dd.z; Areg[4*j4+3] += cr*dd.w;
                const float4 uu = *(const float4*)&vuw[cb + 4*j4];
                float4 u = *(float4*)&U[r*LDT + cb + 4*j4];
                u.x -= cr*uu.x; u.y -= cr*uu.y; u.z -= cr*uu.z; u.w -= cr*uu.w;
                *(float4*)&U[r*LDT + cb + 4*j4] = u;
                const float4 q1 = *(const float4*)&vg1[cb + 4*j4];
                const float4 q2 = *(const float4*)&vg2[cb + 4*j4];
                Greg[4*j4]   -= ars*q1.x + br_*q2.x;
                Greg[4*j4+1] -= ars*q1.y + br_*q2.y;
                Greg[4*j4+2] -= ars*q1.z + br_*q2.z;
                Greg[4*j4+3] -= ars*q1.w + br_*q2.w;
            }
            // write-through A^T
            #pragma unroll
            for (int j = 0; j < 32; ++j) At[(cb + j)*LDT + r] = Areg[j];
            // fused next-step az = A_new z_next (z prefetched in P4)
            if (e + 1 < EE) {
                float s = 0.f;
                #pragma unroll
                for (int j4 = 0; j4 < 8; ++j4) {
                    const float4 x = *(const float4*)&vz[cb + 4*j4];
                    s += Areg[4*j4]*x.x + Areg[4*j4+1]*x.y + Areg[4*j4+2]*x.z + Areg[4*j4+3]*x.w;
                }
                atomicAdd(&vaz[r], s);
            }
        }
        __syncthreads();
    }

    // epilogue: post_mean from Areg
    {
        float* dst = out + (size_t)b*(MM*CC) + r*CC + cb;
        #pragma unroll
        for (int j4 = 0; j4 < 8; ++j4) {
            float4 v; v.x = Areg[4*j4]; v.y = Areg[4*j4+1]; v.z = Areg[4*j4+2]; v.w = Areg[4*j4+3];
            *(float4*)&dst[4*j4] = v;
        }
    }
    // post_cov from U (LDS)
    {
        float* dst = out + (size_t)BB*(MM*CC) + (size_t)b*(MM*MM) + r*MM + cb;
        #pragma unroll
        for (int j4 = 0; j4 < 8; ++j4)
            *(float4*)&dst[4*j4] = *(const float4*)&U[r*LDT + cb + 4*j4];
    }
    // dkl = mean_b[ C*sum(q/p) + sum((A-A0)^2)/p - C*M + C*sum(log p - log q) ]
    {
        const float inv_p = 1.0f / pvar;
        float acc = 0.f;
        const float* src = mean0 + r*CC + cb;
        #pragma unroll
        for (int j4 = 0; j4 < 8; ++j4) {
            const float4 a0 = *(const float4*)&src[4*j4];
            const float dx = Areg[4*j4]   - a0.x, dy = Areg[4*j4+1] - a0.y;
            const float dz = Areg[4*j4+2] - a0.z, dw = Areg[4*j4+3] - a0.w;
            acc += dx*dx + dy*dy + dz*dz + dw*dw;
        }
        float local = acc * inv_p;
        if (q == (r >> 5)) {   // owner of diagonal element of row r
            const float qd = U[r*LDT + r];
            local += (float)CC * (qd*inv_p + logf(pvar) - logf(qd));
        }
        #pragma unroll
        for (int m2 = 1; m2 < 64; m2 <<= 1) local += __shfl_xor(local, m2, 64);
        if (l == 0) scal[6 + w] = local;
        __syncthreads();
        if (t == 0) {
            float tot = 0.f;
            #pragma unroll
            for (int i = 0; i < 8; ++i) tot += scal[6 + i];
            tot -= (float)(CC*MM);
            atomicAdd(out + (size_t)2*BB*MM*CC, tot * (1.0f/(float)BB));
        }
    }
}

extern "C" void kernel_launch(void* const* d_in, const int* in_sizes, int n_in,
                              void* d_out, int out_size, void* d_ws, size_t ws_size,
                              hipStream_t stream) {
    (void)in_sizes; (void)n_in; (void)out_size;
    const float* zin   = (const float*)d_in[0];
    const float* mean0 = (const float*)d_in[1];
    const float* lvar  = (const float*)d_in[2];
    float* out = (float*)d_out;
    float* dkl = out + (size_t)2*BB*MM*CC;
    const int use_ws = (d_ws != nullptr && ws_size >= (size_t)MM*MM*4) ? 1 : 0;
    float* ginv0 = (float*)d_ws;

    hipFuncSetAttribute((const void*)gpm_setup, hipFuncAttributeMaxDynamicSharedMemorySize, SMEM_BYTES);
    hipFuncSetAttribute((const void*)gpm_main,  hipFuncAttributeMaxDynamicSharedMemorySize, SMEM_BYTES);

    hipMemsetAsync(dkl, 0, sizeof(float), stream);
    if (use_ws)
        gpm_setup<<<1, 512, SMEM_BYTES, stream>>>(mean0, ginv0);
    gpm_main<<<BB, 512, SMEM_BYTES, stream>>>(zin, mean0, lvar, out, ginv0, use_ws);
}

// Round 12
// 1367.344 us; speedup vs baseline: 2.8073x; 1.0712x over previous
//
#include <hip/hip_runtime.h>
#include <math.h>

// Problem constants (E,B,M,C) = (64, 512, 128, 128), sigma=0.5, eps=1e-6
#define MM   128
#define CC   128
#define EE   64
#define BB   512
#define LDT  132          // padded row stride for At/U in LDS (measured conflict-free r4-r11)
#define SIG2 0.25f
#define SIG4 0.0625f
#define EPSV 1e-6f

// LDS layout (floats): At[128][132] + U[128][132] + 9 vectors of 128 + 32 scalars
#define AT_OFF   0
#define U_OFF    (128*LDT)
#define VEC_BASE (2*128*LDT)
#define VEC(i)   (VEC_BASE + (i)*128)
// vec: 0 vz, 1 vaz, 2 vw0(w), 3 vt2(z->dl), 4 vuw, 5 g1-bank0, 6 g1-bank1, 7 g2-bank0, 8 g2-bank1
#define SC_OFF   (VEC_BASE + 9*128)
// scal: [0..7]=bank0, [8..15]=bank1 ([+0]=sig [+1]=d2 [+2]=s_uwg2 [+3]=s_vg1/SIG4 [+4]=s_uwg1/SIG2)
//       [16..23]=epilogue wave sums, [30]=GJ pivot
#define SMEM_FLOATS (SC_OFF + 32)
#define SMEM_BYTES  (SMEM_FLOATS * 4)    // 139,936 B -> 1 block/CU

// ---------------------------------------------------------------------------
// 512 threads = 8 waves: w = t>>6, l = t&63
//   r = 64*(w&1)+l (row owned), q = w>>1 (0..3), cb = 32*q (column chunk)
// REGISTERS: Areg[32] + Greg[32] = 64 state (~110 live). U in LDS.
// 3-PHASE SCHEDULE (r10/r11 measured: time ∝ phase count; 9ph=2218,
// 6ph=1501, 4ph=1233):
//   Pa: Greg -= rank2(prev-step g1,g2,scalars) ; w = Ginv_new az ;
//       vt2=z ; zero vuw
//   Pb: dl=z-At w ; uw=U w ; g1c=Ginv w ; sig,s_vg1 partials ;
//       zero prev g1/g2/scal banks + vaz ; prefetch z_next
//   Pc: g2=Ginv uw ; s_uwg2 (from g2-partials), d2, s_uwg1 ; A += c dl^T ;
//       U -= c uw^T ; At write ; az_next = A_new z_next ; zero vw0
// The Ginv rank-2 update is DEFERRED to the next step's Pa (Ginv is only
// consumed there), removing the dedicated update phase. Cross-step values
// (g1, g2, scalars) are parity-double-buffered (bank = e&1). Zero-filled
// banks at e=0 degenerate the update to a no-op (ar_=br_=0, idet=-1).
// v = A*delta ≈ SIG2*w identity carried from r11 (absmax unchanged).
// ---------------------------------------------------------------------------
#define KATTR __attribute__((amdgpu_flat_work_group_size(512, 512), amdgpu_waves_per_eu(1, 2)))

// In-place Gauss-Jordan inverse of (A A^T + SIG2*I), 512 threads.
// A staged row-major in T=[128][LDT]; destroys T; leaves Ginv in T.
// Map: rg = t>>2, cq = t&3, ccb = 32*cq.   (verbatim from passing r5-r11)
__device__ __forceinline__ void ginv_inplace(float* sm, const int t) {
    float* T   = sm + AT_OFF;
    float* piv = sm + SC_OFF + 30;
    const int rg = t >> 2, cq = t & 3, ccb = cq << 5;
    float Gacc[32];
    #pragma unroll
    for (int j = 0; j < 32; ++j) Gacc[j] = 0.f;
    #pragma unroll 1
    for (int cc = 0; cc < 32; ++cc) {
        const float4 ar = *(const float4*)&T[rg*LDT + 4*cc];
        #pragma unroll
        for (int j = 0; j < 32; ++j) {
            const float4 br = *(const float4*)&T[(ccb + j)*LDT + 4*cc];
            Gacc[j] += ar.x*br.x + ar.y*br.y + ar.z*br.z + ar.w*br.w;
        }
    }
    #pragma unroll
    for (int j = 0; j < 32; ++j)
        if (ccb + j == rg) Gacc[j] += SIG2;
    __syncthreads();
    #pragma unroll
    for (int j4 = 0; j4 < 8; ++j4) {
        float4 v; v.x = Gacc[4*j4]; v.y = Gacc[4*j4+1]; v.z = Gacc[4*j4+2]; v.w = Gacc[4*j4+3];
        *(float4*)&T[rg*LDT + ccb + 4*j4] = v;
    }
    #pragma unroll 1
    for (int k = 0; k < 128; ++k) {
        const int kq = k >> 5;
        __syncthreads();
        if (rg == k && cq == kq) piv[0] = 1.0f / T[k*LDT + k];
        __syncthreads();
        if (rg == k) {
            const float pinv = piv[0];
            #pragma unroll
            for (int j4 = 0; j4 < 8; ++j4) {
                float4 g = *(float4*)&T[k*LDT + ccb + 4*j4];
                g.x *= pinv; g.y *= pinv; g.z *= pinv; g.w *= pinv;
                *(float4*)&T[k*LDT + ccb + 4*j4] = g;
            }
            if (cq == kq) T[k*LDT + k] = pinv;   // identity-column trick
        }
        __syncthreads();
        const float f = (rg == k) ? 0.f : T[rg*LDT + k];
        __syncthreads();
        if (rg != k) {
            #pragma unroll
            for (int j4 = 0; j4 < 8; ++j4) {
                float4 own = *(float4*)&T[rg*LDT + ccb + 4*j4];
                const float4 pv = *(const float4*)&T[k*LDT + ccb + 4*j4];
                own.x -= f*pv.x; own.y -= f*pv.y; own.z -= f*pv.z; own.w -= f*pv.w;
                *(float4*)&T[rg*LDT + ccb + 4*j4] = own;
            }
            if (cq == kq) T[rg*LDT + k] -= f;    // blind gave f - f*pinv; want -f*pinv
        }
    }
    __syncthreads();
}

__global__ KATTR void gpm_setup(const float* __restrict__ mean0,
                                float* __restrict__ ginv0) {
    extern __shared__ float sm[];
    float* T = sm + AT_OFF;
    const int t = threadIdx.x;
    const int rg = t >> 2, cq = t & 3, ccb = cq << 5;
    const float* src = mean0 + rg*CC + ccb;
    #pragma unroll
    for (int j4 = 0; j4 < 8; ++j4)
        *(float4*)&T[rg*LDT + ccb + 4*j4] = *(const float4*)&src[4*j4];
    __syncthreads();
    ginv_inplace(sm, t);
    #pragma unroll
    for (int j4 = 0; j4 < 8; ++j4)
        *(float4*)&ginv0[rg*CC + ccb + 4*j4] = *(const float4*)&T[rg*LDT + ccb + 4*j4];
}

// 3-level shuffle (8-lane groups) then 1-in-8 lanes atomic into a scalar slot
#define SC_ADD(base, slot, val) { float v_ = (val);                           \
    v_ += __shfl_xor(v_, 1, 64); v_ += __shfl_xor(v_, 2, 64);                 \
    v_ += __shfl_xor(v_, 4, 64);                                              \
    if ((l & 7) == 0) atomicAdd(&(base)[slot], v_); }

__global__ KATTR void gpm_main(
        const float* __restrict__ zin, const float* __restrict__ mean0,
        const float* __restrict__ lvar, float* __restrict__ out,
        const float* __restrict__ ginv0, const int use_ws) {
    extern __shared__ float sm[];
    float* At  = sm + AT_OFF;
    float* U   = sm + U_OFF;
    float* vz  = sm + VEC(0);
    float* vaz = sm + VEC(1);
    float* vw0 = sm + VEC(2);
    float* vt2 = sm + VEC(3);   // z copy in Pa; dl after Pb
    float* vuw = sm + VEC(4);
    float* scal = sm + SC_OFF;

    const int t = threadIdx.x, b = blockIdx.x;
    const int w = t >> 6, l = t & 63;
    const int r  = ((w & 1) << 6) | l;
    const int q  = w >> 1;
    const int cb = q << 5;

    // zero accumulator vectors VEC(1)..VEC(8) (1024 floats) + scalar slots
    sm[VEC(1) + t] = 0.f;
    sm[VEC(1) + 512 + t] = 0.f;
    if (t < 32) scal[t] = 0.f;
    if (t == 0) { scal[0] = SIG2; scal[8] = SIG2; }   // sig slots of both banks

    const float pvar = expf(lvar[0]) + EPSV;

    float Areg[32], Greg[32];

    if (use_ws) {
        const float* src = ginv0 + r*CC + cb;
        #pragma unroll
        for (int j4 = 0; j4 < 8; ++j4) {
            const float4 v = *(const float4*)&src[4*j4];
            Greg[4*j4] = v.x; Greg[4*j4+1] = v.y; Greg[4*j4+2] = v.z; Greg[4*j4+3] = v.w;
        }
    } else {
        // fallback: stage A into At buffer, invert in place, read back
        const float* src = mean0 + r*CC + cb;
        #pragma unroll
        for (int j4 = 0; j4 < 8; ++j4)
            *(float4*)&At[r*LDT + cb + 4*j4] = *(const float4*)&src[4*j4];
        __syncthreads();
        ginv_inplace(sm, t);
        #pragma unroll
        for (int j4 = 0; j4 < 8; ++j4) {
            const float4 v = *(const float4*)&At[r*LDT + cb + 4*j4];
            Greg[4*j4] = v.x; Greg[4*j4+1] = v.y; Greg[4*j4+2] = v.z; Greg[4*j4+3] = v.w;
        }
        __syncthreads();       // done reading Ginv before At is overwritten
    }
    {
        const float* src = mean0 + r*CC + cb;
        #pragma unroll
        for (int j4 = 0; j4 < 8; ++j4) {
            const float4 v = *(const float4*)&src[4*j4];
            Areg[4*j4] = v.x; Areg[4*j4+1] = v.y; Areg[4*j4+2] = v.z; Areg[4*j4+3] = v.w;
        }
    }
    // U = pvar * I  (row r, cols [cb,cb+32))
    {
        const float4 z4 = {0.f, 0.f, 0.f, 0.f};
        #pragma unroll
        for (int j4 = 0; j4 < 8; ++j4)
            *(float4*)&U[r*LDT + cb + 4*j4] = z4;
        if (r >= cb && r < cb + 32) U[r*LDT + r] = pvar;
    }
    // At = A^T (consecutive lanes -> consecutive addresses)
    #pragma unroll
    for (int j = 0; j < 32; ++j) At[(cb + j)*LDT + r] = Areg[j];
    if (t < 32)
        *(float4*)&vz[4*t] = *(const float4*)&zin[(size_t)b*CC + 4*t];
    __syncthreads();

    // P0 (prologue): az(0) = A z0
    {
        float s = 0.f;
        #pragma unroll
        for (int j4 = 0; j4 < 8; ++j4) {
            const float4 x = *(const float4*)&vz[cb + 4*j4];
            s += Areg[4*j4]*x.x + Areg[4*j4+1]*x.y + Areg[4*j4+2]*x.z + Areg[4*j4+3]*x.w;
        }
        atomicAdd(&vaz[r], s);
    }
    __syncthreads();

    #pragma unroll 1
    for (int e = 0; e < EE; ++e) {
        const int p  = e & 1;
        const int pp = p ^ 1;
        float* g1p = sm + VEC(5) + (p  << 7);
        float* g1q = sm + VEC(5) + (pp << 7);
        float* g2p = sm + VEC(7) + (p  << 7);
        float* g2q = sm + VEC(7) + (pp << 7);
        float* scp = scal + 8*p;
        float* scq = scal + 8*pp;
        // ---- Pa: Greg -= rank2(prev) ; w = Ginv_new az ; vt2 = z ; zero vuw ----
        {
            const float sigp    = scq[0];
            const float inv_sig = 1.0f / sigp;
            const float d2v     = scq[1];
            const float s_uwg2  = scq[2];
            const float s_vg1   = SIG4 * scq[3];
            const float s_uwg1  = SIG2 * scq[4];
            const float b11  = s_vg1 - d2v;
            const float b12  = 1.0f + s_uwg1*inv_sig;
            const float b22  = s_uwg2*inv_sig*inv_sig;
            const float idet = 1.0f / (b11*b22 - b12*b12);
            const float K11 = b22*idet, K12v = -b12*idet, K22 = b11*idet;
            const float k12s = K12v*inv_sig, k22s = K22*inv_sig*inv_sig;
            const float g1r = SIG2 * g1q[r];
            const float g2r = g2q[r];
            const float ar_ = K11*g1r + k12s*g2r;
            const float br_ = k12s*g1r + k22s*g2r;
            const float ars = ar_ * SIG2;
            float s = 0.f;
            #pragma unroll
            for (int j4 = 0; j4 < 8; ++j4) {
                const float4 q1 = *(const float4*)&g1q[cb + 4*j4];
                const float4 q2 = *(const float4*)&g2q[cb + 4*j4];
                Greg[4*j4]   -= ars*q1.x + br_*q2.x;
                Greg[4*j4+1] -= ars*q1.y + br_*q2.y;
                Greg[4*j4+2] -= ars*q1.z + br_*q2.z;
                Greg[4*j4+3] -= ars*q1.w + br_*q2.w;
                const float4 x = *(const float4*)&vaz[cb + 4*j4];
                s += Greg[4*j4]*x.x + Greg[4*j4+1]*x.y + Greg[4*j4+2]*x.z + Greg[4*j4+3]*x.w;
            }
            atomicAdd(&vw0[r], s);
            if (t < 128) { vt2[t] = vz[t]; vuw[t] = 0.f; }
        }
        __syncthreads();
        // ---- Pb: dl=z-At w ; uw=U w ; g1c=Ginv w ; sig,s_vg1 ; zero prev banks + vaz ; prefetch z ----
        {
            float s1 = 0.f, s2 = 0.f, s3 = 0.f;
            #pragma unroll
            for (int j4 = 0; j4 < 8; ++j4) {
                const float4 a = *(const float4*)&At[r*LDT + cb + 4*j4];
                const float4 u = *(const float4*)&U[r*LDT + cb + 4*j4];
                const float4 x = *(const float4*)&vw0[cb + 4*j4];
                s1 += a.x*x.x + a.y*x.y + a.z*x.z + a.w*x.w;
                s2 += u.x*x.x + u.y*x.y + u.z*x.z + u.w*x.w;
                s3 += Greg[4*j4]*x.x + Greg[4*j4+1]*x.y + Greg[4*j4+2]*x.z + Greg[4*j4+3]*x.w;
            }
            atomicAdd(&vt2[r], -s1);
            atomicAdd(&vuw[r], s2);
            atomicAdd(&g1p[r], s3);
            const float w_r = vw0[r];
            SC_ADD(scp, 0, s2 * w_r);                  // sig partial (wT U w)
            SC_ADD(scp, 3, s3 * w_r);                  // s_vg1 / SIG4 partial (wT Ginv w)
            if (t < 128) { g1q[t] = 0.f; g2q[t] = 0.f; vaz[t] = 0.f; }
            if (t == 448) { scq[0] = SIG2; scq[1] = 0.f; scq[2] = 0.f; scq[3] = 0.f; scq[4] = 0.f; }
            if (t < 32 && e + 1 < EE)
                *(float4*)&vz[4*t] = *(const float4*)&zin[((size_t)(e+1)*BB + b)*CC + 4*t];
        }
        __syncthreads();
        // ---- Pc: g2=Ginv uw ; s_uwg2,d2,s_uwg1 ; update A,U ; At write ; az_next ; zero vw0 ----
        {
            float s = 0.f;
            #pragma unroll
            for (int j4 = 0; j4 < 8; ++j4) {
                const float4 x = *(const float4*)&vuw[cb + 4*j4];
                s += Greg[4*j4]*x.x + Greg[4*j4+1]*x.y + Greg[4*j4+2]*x.z + Greg[4*j4+3]*x.w;
            }
            atomicAdd(&g2p[r], s);
            SC_ADD(scp, 2, s * vuw[r]);                // s_uwg2 partial (uwT Ginv uw)
            if (t < 128) {
                float d_ = vt2[t]; d_ *= d_;
                d_ += __shfl_xor(d_, 1, 64); d_ += __shfl_xor(d_, 2, 64); d_ += __shfl_xor(d_, 4, 64);
                if ((l & 7) == 0) atomicAdd(&scp[1], d_);        // d2
                float p_ = g1p[t] * vuw[t];
                p_ += __shfl_xor(p_, 1, 64); p_ += __shfl_xor(p_, 2, 64); p_ += __shfl_xor(p_, 4, 64);
                if ((l & 7) == 0) atomicAdd(&scp[4], p_);        // s_uwg1 / SIG2
                vw0[t] = 0.f;
            }
            const float sig = scp[0];                  // accumulated in Pb
            const float inv_sig = 1.0f / sig;
            const float cr = vuw[r] * inv_sig;
            #pragma unroll
            for (int j4 = 0; j4 < 8; ++j4) {
                const float4 dd = *(const float4*)&vt2[cb + 4*j4];
                Areg[4*j4]   += cr*dd.x; Areg[4*j4+1] += cr*dd.y;
                Areg[4*j4+2] += cr*dd.z; Areg[4*j4+3] += cr*dd.w;
                const float4 uu = *(const float4*)&vuw[cb + 4*j4];
                float4 u = *(float4*)&U[r*LDT + cb + 4*j4];
                u.x -= cr*uu.x; u.y -= cr*uu.y; u.z -= cr*uu.z; u.w -= cr*uu.w;
                *(float4*)&U[r*LDT + cb + 4*j4] = u;
            }
            // write-through A^T
            #pragma unroll
            for (int j = 0; j < 32; ++j) At[(cb + j)*LDT + r] = Areg[j];
            // fused next-step az = A_new z_next (z prefetched in Pb)
            if (e + 1 < EE) {
                float s2 = 0.f;
                #pragma unroll
                for (int j4 = 0; j4 < 8; ++j4) {
                    const float4 x = *(const float4*)&vz[cb + 4*j4];
                    s2 += Areg[4*j4]*x.x + Areg[4*j4+1]*x.y + Areg[4*j4+2]*x.z + Areg[4*j4+3]*x.w;
                }
                atomicAdd(&vaz[r], s2);
            }
        }
        __syncthreads();
    }

    // epilogue: post_mean from Areg
    {
        float* dst = out + (size_t)b*(MM*CC) + r*CC + cb;
        #pragma unroll
        for (int j4 = 0; j4 < 8; ++j4) {
            float4 v; v.x = Areg[4*j4]; v.y = Areg[4*j4+1]; v.z = Areg[4*j4+2]; v.w = Areg[4*j4+3];
            *(float4*)&dst[4*j4] = v;
        }
    }
    // post_cov from U (LDS)
    {
        float* dst = out + (size_t)BB*(MM*CC) + (size_t)b*(MM*MM) + r*MM + cb;
        #pragma unroll
        for (int j4 = 0; j4 < 8; ++j4)
            *(float4*)&dst[4*j4] = *(const float4*)&U[r*LDT + cb + 4*j4];
    }
    // dkl = mean_b[ C*sum(q/p) + sum((A-A0)^2)/p - C*M + C*sum(log p - log q) ]
    {
        const float inv_p = 1.0f / pvar;
        float acc = 0.f;
        const float* src = mean0 + r*CC + cb;
        #pragma unroll
        for (int j4 = 0; j4 < 8; ++j4) {
            const float4 a0 = *(const float4*)&src[4*j4];
            const float dx = Areg[4*j4]   - a0.x, dy = Areg[4*j4+1] - a0.y;
            const float dz = Areg[4*j4+2] - a0.z, dw = Areg[4*j4+3] - a0.w;
            acc += dx*dx + dy*dy + dz*dz + dw*dw;
        }
        float local = acc * inv_p;
        if (q == (r >> 5)) {   // owner of diagonal element of row r
            const float qd = U[r*LDT + r];
            local += (float)CC * (qd*inv_p + logf(pvar) - logf(qd));
        }
        #pragma unroll
        for (int m2 = 1; m2 < 64; m2 <<= 1) local += __shfl_xor(local, m2, 64);
        if (l == 0) scal[16 + w] = local;
        __syncthreads();
        if (t == 0) {
            float tot = 0.f;
            #pragma unroll
            for (int i = 0; i < 8; ++i) tot += scal[16 + i];
            tot -= (float)(CC*MM);
            atomicAdd(out + (size_t)2*BB*MM*CC, tot * (1.0f/(float)BB));
        }
    }
}

extern "C" void kernel_launch(void* const* d_in, const int* in_sizes, int n_in,
                              void* d_out, int out_size, void* d_ws, size_t ws_size,
                              hipStream_t stream) {
    (void)in_sizes; (void)n_in; (void)out_size;
    const float* zin   = (const float*)d_in[0];
    const float* mean0 = (const float*)d_in[1];
    const float* lvar  = (const float*)d_in[2];
    float* out = (float*)d_out;
    float* dkl = out + (size_t)2*BB*MM*CC;
    const int use_ws = (d_ws != nullptr && ws_size >= (size_t)MM*MM*4) ? 1 : 0;
    float* ginv0 = (float*)d_ws;

    hipFuncSetAttribute((const void*)gpm_setup, hipFuncAttributeMaxDynamicSharedMemorySize, SMEM_BYTES);
    hipFuncSetAttribute((const void*)gpm_main,  hipFuncAttributeMaxDynamicSharedMemorySize, SMEM_BYTES);

    hipMemsetAsync(dkl, 0, sizeof(float), stream);
    if (use_ws)
        gpm_setup<<<1, 512, SMEM_BYTES, stream>>>(mean0, ginv0);
    gpm_main<<<BB, 512, SMEM_BYTES, stream>>>(zin, mean0, lvar, out, ginv0, use_ws);
}